// Round 7
// baseline (287.610 us; speedup 1.0000x reference)
//
#include <hip/hip_runtime.h>
#include <cstdint>
#include <cstddef>

typedef __bf16 bf16;
typedef __bf16 bf16x8 __attribute__((ext_vector_type(8)));
typedef float f32x4 __attribute__((ext_vector_type(4)));

#define DEVI static __device__ __forceinline__

// pack two f32 -> two bf16 (RTNE) in one uint
DEVI unsigned int cvt_pk_bf16(float lo, float hi) {
  unsigned int bl = __float_as_uint(lo);
  bl += 0x7fffu + ((bl >> 16) & 1u);
  unsigned int bh = __float_as_uint(hi);
  bh += 0x7fffu + ((bh >> 16) & 1u);
  return (bl >> 16) | (bh & 0xffff0000u);
}
DEVI float bf_lo(unsigned int u) { return __uint_as_float(u << 16); }
DEVI float bf_hi(unsigned int u) { return __uint_as_float(u & 0xffff0000u); }

// ---------------------------------------------------------------------------
// W transpose prepass: W (1024x1024 f32, [k][n]) -> Wt (bf16 [n][k]).
// ---------------------------------------------------------------------------
__global__ __launch_bounds__(256) void wtr_k(
    const float* __restrict__ Wq, const float* __restrict__ Wk,
    const float* __restrict__ Wv, const float* __restrict__ Wo,
    bf16* __restrict__ Wt)
{
  const int z = blockIdx.z;
  const float* W = (z == 0) ? Wq : (z == 1) ? Wk : (z == 2) ? Wv : Wo;
  bf16* out = Wt + ((size_t)z << 20);
  const int n0 = blockIdx.x * 64, k0 = blockIdx.y * 64;
  __shared__ bf16 Ts[64 * 72];
  const int tid = threadIdx.x;
  #pragma unroll
  for (int i = 0; i < 4; ++i) {
    int t = tid + i * 256;
    int kr = t >> 4, nc = t & 15;
    float4 v = *(const float4*)(W + (size_t)(k0 + kr) * 1024 + n0 + nc * 4);
    Ts[(nc * 4 + 0) * 72 + kr] = (bf16)v.x;
    Ts[(nc * 4 + 1) * 72 + kr] = (bf16)v.y;
    Ts[(nc * 4 + 2) * 72 + kr] = (bf16)v.z;
    Ts[(nc * 4 + 3) * 72 + kr] = (bf16)v.w;
  }
  __syncthreads();
  const int n = tid >> 2, kc = tid & 3;
  *(uint4*)(out + (size_t)(n0 + n) * 1024 + k0 + kc * 16) =
      *(const uint4*)(&Ts[n * 72 + kc * 16]);
  *(uint4*)(out + (size_t)(n0 + n) * 1024 + k0 + kc * 16 + 8) =
      *(const uint4*)(&Ts[n * 72 + kc * 16 + 8]);
}

// ---------------------------------------------------------------------------
// Fused projection GEMM, f32 A staged inline to bf16, register prefetch.
// grid (16,32,3): z=0 Q->qh, z=1 K->kh, z=2 V->vT(B,H,HD,S).
// ---------------------------------------------------------------------------
__global__ __launch_bounds__(256) void proj_gemm_k(
    const float* __restrict__ Q, const float* __restrict__ K,
    const float* __restrict__ V, const bf16* __restrict__ Wt,
    const float* __restrict__ bq, const float* __restrict__ bk,
    const float* __restrict__ bv, bf16* __restrict__ outbase)
{
  const int z = blockIdx.z;
  const float* A = (z == 0) ? Q : (z == 1) ? K : V;
  const bf16* Bt = Wt + ((size_t)z << 20);
  const float* bias = (z == 0) ? bq : (z == 1) ? bk : bv;
  bf16* outb = outbase + ((size_t)z << 21);

  __shared__ __align__(16) char sm[10240];
  bf16* As = (bf16*)sm;
  bf16* Bs = As + 64 * 40;
  bf16* T  = (bf16*)sm;

  const int tid = threadIdx.x, lane = tid & 63, wid = tid >> 6;
  const int q4 = lane >> 4, n16 = lane & 15;
  const int wm = wid >> 1, wn = wid & 1;
  const int m0 = blockIdx.y * 64, n0 = blockIdx.x * 64;
  const int brow = tid >> 2, bc = tid & 3;
  f32x4 acc[2][2] = {};

  float4 aR0 = *(const float4*)(A + (size_t)(m0 + brow) * 1024 + bc * 8);
  float4 aR1 = *(const float4*)(A + (size_t)(m0 + brow) * 1024 + bc * 8 + 4);
  uint4 bR = *(const uint4*)(Bt + (size_t)(n0 + brow) * 1024 + bc * 8);
  for (int kb = 0; kb < 32; ++kb) {
    __syncthreads();
    *(uint2*)(&As[brow * 40 + bc * 8]) =
        make_uint2(cvt_pk_bf16(aR0.x, aR0.y), cvt_pk_bf16(aR0.z, aR0.w));
    *(uint2*)(&As[brow * 40 + bc * 8 + 4]) =
        make_uint2(cvt_pk_bf16(aR1.x, aR1.y), cvt_pk_bf16(aR1.z, aR1.w));
    *(uint4*)(&Bs[brow * 40 + bc * 8]) = bR;
    __syncthreads();
    if (kb < 31) {
      const int k1 = (kb + 1) * 32;
      aR0 = *(const float4*)(A + (size_t)(m0 + brow) * 1024 + k1 + bc * 8);
      aR1 = *(const float4*)(A + (size_t)(m0 + brow) * 1024 + k1 + bc * 8 + 4);
      bR  = *(const uint4*)(Bt + (size_t)(n0 + brow) * 1024 + k1 + bc * 8);
    }
    bf16x8 af[2], bfv[2];
    #pragma unroll
    for (int rt = 0; rt < 2; ++rt)
      af[rt] = *(const bf16x8*)(&As[(wm * 32 + rt * 16 + n16) * 40 + q4 * 8]);
    #pragma unroll
    for (int ct = 0; ct < 2; ++ct)
      bfv[ct] = *(const bf16x8*)(&Bs[(wn * 32 + ct * 16 + n16) * 40 + q4 * 8]);
    #pragma unroll
    for (int rt = 0; rt < 2; ++rt)
      #pragma unroll
      for (int ct = 0; ct < 2; ++ct)
        acc[rt][ct] = __builtin_amdgcn_mfma_f32_16x16x32_bf16(af[rt], bfv[ct], acc[rt][ct], 0, 0, 0);
  }

  if (z < 2) {   // (B,H,S,HD)
    #pragma unroll
    for (int ct = 0; ct < 2; ++ct) {
      int col = n0 + wn * 32 + ct * 16 + n16;
      float bvl = bias[col];
      int h = col >> 6, d = col & 63;
      #pragma unroll
      for (int rt = 0; rt < 2; ++rt) {
        #pragma unroll
        for (int r = 0; r < 4; ++r) {
          int row = m0 + wm * 32 + rt * 16 + q4 * 4 + r;
          int b2 = row >> 10, s = row & 1023;
          outb[((size_t)((b2 * 16 + h) * 1024 + s) << 6) + d] =
              (bf16)(acc[rt][ct][r] + bvl);
        }
      }
    }
  } else {       // transpose -> (B,H,HD,S)
    __syncthreads();
    #pragma unroll
    for (int ct = 0; ct < 2; ++ct) {
      int cl = wn * 32 + ct * 16 + n16;
      float bvl = bias[n0 + cl];
      #pragma unroll
      for (int rt = 0; rt < 2; ++rt)
        #pragma unroll
        for (int r = 0; r < 4; ++r) {
          int rl = wm * 32 + rt * 16 + q4 * 4 + r;
          T[rl * 66 + cl] = (bf16)(acc[rt][ct][r] + bvl);
        }
    }
    __syncthreads();
    #pragma unroll
    for (int i = 0; i < 16; ++i) {
      int f = tid + i * 256;
      int nl = f >> 6, sl = f & 63;
      int col = n0 + nl, row = m0 + sl;
      int b2 = row >> 10, s = row & 1023;
      int h = col >> 6, d = col & 63;
      outb[((size_t)((b2 * 16 + h) * 64 + d) << 10) + s] = T[sl * 66 + nl];
    }
  }
}

// ---------------------------------------------------------------------------
// Output GEMM: d_out = oat(2048x1024 bf16) @ WoT + bo, f32 out. Prefetched.
// ---------------------------------------------------------------------------
__global__ __launch_bounds__(256) void out_gemm_k(
    const bf16* __restrict__ Ab, const bf16* __restrict__ Bt,
    const float* __restrict__ bias, float* __restrict__ outf)
{
  __shared__ __align__(16) char sm[10240];
  bf16* As = (bf16*)sm;
  bf16* Bs = As + 64 * 40;
  const int tid = threadIdx.x, lane = tid & 63, wid = tid >> 6;
  const int q4 = lane >> 4, n16 = lane & 15;
  const int wm = wid >> 1, wn = wid & 1;
  const int m0 = blockIdx.y * 64, n0 = blockIdx.x * 64;
  const int brow = tid >> 2, bc = tid & 3;
  f32x4 acc[2][2] = {};

  uint4 aR = *(const uint4*)(Ab + (size_t)(m0 + brow) * 1024 + bc * 8);
  uint4 bR = *(const uint4*)(Bt + (size_t)(n0 + brow) * 1024 + bc * 8);
  for (int kb = 0; kb < 32; ++kb) {
    __syncthreads();
    *(uint4*)(&As[brow * 40 + bc * 8]) = aR;
    *(uint4*)(&Bs[brow * 40 + bc * 8]) = bR;
    __syncthreads();
    if (kb < 31) {
      const int k1 = (kb + 1) * 32;
      aR = *(const uint4*)(Ab + (size_t)(m0 + brow) * 1024 + k1 + bc * 8);
      bR = *(const uint4*)(Bt + (size_t)(n0 + brow) * 1024 + k1 + bc * 8);
    }
    bf16x8 af[2], bfv[2];
    #pragma unroll
    for (int rt = 0; rt < 2; ++rt)
      af[rt] = *(const bf16x8*)(&As[(wm * 32 + rt * 16 + n16) * 40 + q4 * 8]);
    #pragma unroll
    for (int ct = 0; ct < 2; ++ct)
      bfv[ct] = *(const bf16x8*)(&Bs[(wn * 32 + ct * 16 + n16) * 40 + q4 * 8]);
    #pragma unroll
    for (int rt = 0; rt < 2; ++rt)
      #pragma unroll
      for (int ct = 0; ct < 2; ++ct)
        acc[rt][ct] = __builtin_amdgcn_mfma_f32_16x16x32_bf16(af[rt], bfv[ct], acc[rt][ct], 0, 0, 0);
  }
  #pragma unroll
  for (int ct = 0; ct < 2; ++ct) {
    int col = n0 + wn * 32 + ct * 16 + n16;
    float bvl = bias[col];
    #pragma unroll
    for (int rt = 0; rt < 2; ++rt)
      #pragma unroll
      for (int r = 0; r < 4; ++r) {
        int row = m0 + wm * 32 + rt * 16 + q4 * 4 + r;
        outf[(size_t)row * 1024 + col] = acc[rt][ct][r] + bvl;
      }
  }
}

// ---------------------------------------------------------------------------
// per-(b,h,ktile) column sums of v + suffix scan
// ---------------------------------------------------------------------------
__global__ void vtile_sum_k(const bf16* __restrict__ vT, float* __restrict__ Tsum)
{
  int kt = blockIdx.x, h = blockIdx.y, b = blockIdx.z, d = threadIdx.x;
  const bf16* p = vT + (((size_t)(b * 16 + h) * 64 + d) << 10) + kt * 64;
  float s = 0.f;
  #pragma unroll 8
  for (int i = 0; i < 64; ++i) s += (float)p[i];
  Tsum[((b * 16 + h) * 16 + kt) * 64 + d] = s;
}

__global__ void vtail_k(const float* __restrict__ Tsum, float* __restrict__ Vtail)
{
  int h = blockIdx.x, b = blockIdx.y, d = threadIdx.x;
  float c = 0.f;
  Vtail[((b * 16 + h) * 17 + 16) * 64 + d] = 0.f;
  for (int kt = 15; kt >= 0; --kt) {
    c += Tsum[((b * 16 + h) * 16 + kt) * 64 + d];
    Vtail[((b * 16 + h) * 17 + kt) * 64 + d] = c;
  }
}

// ---------------------------------------------------------------------------
// Fused attention: per (qt, head-pair g, b) block, 8 waves (512 thr).
// Per ct tile: [A] QK^T -> Ls (f32 66x66 halo, masked+scaled)
//              [B] 3x3 conv + online-softmax exp -> P (bf16, LDS) + alpha
//              [C] acc rescale + P@V MFMA (V frags straight from global/L2)
// Epilogue: analytic constant tail + head mix + mix_b colsum + DyT -> oat.
// P never touches HBM.
// ---------------------------------------------------------------------------
__global__ __launch_bounds__(512) void attn_k(
    const bf16* __restrict__ qh, const bf16* __restrict__ kh,
    const bf16* __restrict__ vT,
    const float* __restrict__ kq_w, const float* __restrict__ kq_b,
    const float* __restrict__ Vtail,
    const float* __restrict__ mix_w, const float* __restrict__ mix_b,
    const float* __restrict__ dyt_alpha, const float* __restrict__ dyt_w,
    const float* __restrict__ dyt_b, const float* __restrict__ depth_scale,
    bf16* __restrict__ out_attn)
{
  const int qt = blockIdx.x, g = blockIdx.y, b = blockIdx.z;
  const int q0 = qt * 64;
  const int nct = min(qt + 2, 16);
  const int Tc = 1024 - (nct << 6);
  const int tid = threadIdx.x, lane = tid & 63, wid = tid >> 6;
  const int q4 = lane >> 4, n16 = lane & 15;
  const int h0 = 2 * g, b16 = b * 16 + h0;

  __shared__ float Ls[2][66 * 76];          // stride 76: conflict-free phases
  __shared__ bf16 Pb[2][64 * 72];
  __shared__ float alph[2][64], linv[2][64], afin[2][64], twl[2][64];
  float* Ob = &Ls[0][0];                    // [2][64][68] f32, aliases Ls

  // ---- persistent A fragments (q rows fixed per block) ----
  bf16x8 aA[2][2];
  #pragma unroll
  for (int tt = 0; tt < 2; ++tt) {
    int t = wid + tt * 8;
    if (t < 10) {
      int j = t >= 5 ? 1 : 0, rt = t - j * 5;
      const bf16* qbj = qh + ((size_t)(b16 + j) << 16);
      int arc = min(max(q0 - 2 + rt * 16 + n16, 0), 1023);
      aA[tt][0] = *(const bf16x8*)(qbj + arc * 64 + q4 * 8);
      aA[tt][1] = *(const bf16x8*)(qbj + arc * 64 + 32 + q4 * 8);
    }
  }

  // phase-B identity (conv+softmax): wave bj handles head bj, 16-row group
  const int bj = wid >> 2;
  const int rB = (wid & 3) * 16 + (lane >> 2);
  const int qrB = lane & 3;
  float w9[9];
  #pragma unroll
  for (int i = 0; i < 9; ++i) w9[i] = kq_w[(h0 + bj) * 9 + i];
  const float bbj = kq_b[h0 + bj];
  float m_run = -3.0e38f, l_run = 0.f;

  // phase-C identity (PV): wave = (cjj attn-head, co v-head, chf row-half)
  const int cjj = wid & 1, co = (wid >> 1) & 1, chf = wid >> 2;
  const bf16* vbo = vT + ((size_t)(b16 + co) << 16);
  f32x4 acc[2][4] = {};

  for (int ct = 0; ct < nct; ++ct) {
    const int c0 = ct * 64;
    // ---------- phase A: QK^T -> Ls ----------
    #pragma unroll
    for (int tt = 0; tt < 2; ++tt) {
      int t = wid + tt * 8;
      if (t < 10) {
        int j = t >= 5 ? 1 : 0, rt = t - j * 5;
        const bf16* kbj = kh + ((size_t)(b16 + j) << 16);
        uint4 bl0[5], bl1[5];
        #pragma unroll
        for (int c5 = 0; c5 < 5; ++c5) {
          int brc = min(max(c0 - 1 + c5 * 16 + n16, 0), 1023);
          bl0[c5] = *(const uint4*)(kbj + brc * 64 + q4 * 8);
          bl1[c5] = *(const uint4*)(kbj + brc * 64 + 32 + q4 * 8);
        }
        f32x4 s5[5] = {};
        #pragma unroll
        for (int c5 = 0; c5 < 5; ++c5) {
          s5[c5] = __builtin_amdgcn_mfma_f32_16x16x32_bf16(aA[tt][0], *(const bf16x8*)&bl0[c5], s5[c5], 0, 0, 0);
          s5[c5] = __builtin_amdgcn_mfma_f32_16x16x32_bf16(aA[tt][1], *(const bf16x8*)&bl1[c5], s5[c5], 0, 0, 0);
        }
        #pragma unroll
        for (int c5 = 0; c5 < 5; ++c5) {
          int Lcol = c5 * 16 + n16;
          #pragma unroll
          for (int rr = 0; rr < 4; ++rr) {
            int Lrow = rt * 16 + q4 * 4 + rr;
            if (Lrow < 66 && Lcol < 66) {
              int ar = q0 - 2 + Lrow, cg = c0 - 1 + Lcol;
              Ls[j][Lrow * 76 + Lcol] =
                  (cg >= 0 && cg <= ar) ? s5[c5][rr] * 0.125f : 0.f;
            }
          }
        }
      }
    }
    __syncthreads();
    // ---------- phase B: conv + online exp -> Pb, alpha ----------
    {
      const float* L0 = &Ls[bj][rB * 76 + qrB * 16];
      float4 R0[5], R1[5], R2[5];
      #pragma unroll
      for (int i = 0; i < 5; ++i) {
        R0[i] = *(const float4*)(L0 + i * 4);
        R1[i] = *(const float4*)(L0 + 76 + i * 4);
        R2[i] = *(const float4*)(L0 + 152 + i * 4);
      }
      const float* f0 = (const float*)R0;
      const float* f1 = (const float*)R1;
      const float* f2 = (const float*)R2;
      float o[16];
      #pragma unroll
      for (int jj = 0; jj < 16; ++jj)
        o[jj] = bbj + w9[0]*f0[jj] + w9[1]*f0[jj+1] + w9[2]*f0[jj+2]
                    + w9[3]*f1[jj] + w9[4]*f1[jj+1] + w9[5]*f1[jj+2]
                    + w9[6]*f2[jj] + w9[7]*f2[jj+1] + w9[8]*f2[jj+2];
      float t = o[0];
      #pragma unroll
      for (int jj = 1; jj < 16; ++jj) t = fmaxf(t, o[jj]);
      t = fmaxf(t, __shfl_xor(t, 1));
      t = fmaxf(t, __shfl_xor(t, 2));
      float mn = fmaxf(m_run, t);
      float al = __expf(m_run - mn);
      m_run = mn;
      unsigned int p[8];
      #pragma unroll
      for (int jj = 0; jj < 8; ++jj)
        p[jj] = cvt_pk_bf16(__expf(o[2*jj] - mn), __expf(o[2*jj+1] - mn));
      *(uint4*)(&Pb[bj][rB * 72 + qrB * 16])     = *(const uint4*)&p[0];
      *(uint4*)(&Pb[bj][rB * 72 + qrB * 16 + 8]) = *(const uint4*)&p[4];
      float s = 0.f;
      #pragma unroll
      for (int jj = 0; jj < 8; ++jj) s += bf_lo(p[jj]) + bf_hi(p[jj]);
      s += __shfl_xor(s, 1);
      s += __shfl_xor(s, 2);
      l_run = l_run * al + s;
      if (qrB == 0) alph[bj][rB] = al;
    }
    __syncthreads();
    // ---------- phase C: rescale + PV ----------
    {
      float av8[8];
      #pragma unroll
      for (int rt = 0; rt < 2; ++rt)
        #pragma unroll
        for (int rr = 0; rr < 4; ++rr)
          av8[rt*4+rr] = alph[cjj][chf*32 + rt*16 + q4*4 + rr];
      #pragma unroll
      for (int rt = 0; rt < 2; ++rt)
        #pragma unroll
        for (int ctt = 0; ctt < 4; ++ctt)
          #pragma unroll
          for (int rr = 0; rr < 4; ++rr)
            acc[rt][ctt][rr] *= av8[rt*4+rr];
      bf16x8 af[2][2];
      #pragma unroll
      for (int rt = 0; rt < 2; ++rt)
        #pragma unroll
        for (int kk = 0; kk < 2; ++kk)
          af[rt][kk] = *(const bf16x8*)(&Pb[cjj][(chf*32 + rt*16 + n16) * 72 + kk*32 + q4*8]);
      bf16x8 bv[2][4];
      #pragma unroll
      for (int kk = 0; kk < 2; ++kk)
        #pragma unroll
        for (int ctt = 0; ctt < 4; ++ctt)
          bv[kk][ctt] = *(const bf16x8*)(vbo + (size_t)(ctt*16 + n16) * 1024 + c0 + kk*32 + q4*8);
      #pragma unroll
      for (int kk = 0; kk < 2; ++kk)
        #pragma unroll
        for (int rt = 0; rt < 2; ++rt)
          #pragma unroll
          for (int ctt = 0; ctt < 4; ++ctt)
            acc[rt][ctt] = __builtin_amdgcn_mfma_f32_16x16x32_bf16(af[rt][kk], bv[kk][ctt], acc[rt][ctt], 0, 0, 0);
    }
  }

  // ---------- finalize per-row stats (incl. constant tail) ----------
  {
    float mf = (Tc > 0) ? fmaxf(m_run, bbj) : m_run;
    float afv = __expf(m_run - mf);
    float lf = l_run * afv + (float)Tc * __expf(bbj - mf);
    if (qrB == 0) {
      linv[bj][rB] = 1.f / lf;
      afin[bj][rB] = afv;
      twl[bj][rB]  = (Tc > 0) ? __expf(bbj - mf) : 0.f;
    }
  }
  __syncthreads();

  // ---------- mix + tail into Ob ----------
  {
    float lv[8], av[8], tl[8];
    #pragma unroll
    for (int rt = 0; rt < 2; ++rt)
      #pragma unroll
      for (int rr = 0; rr < 4; ++rr) {
        int row = chf*32 + rt*16 + q4*4 + rr;
        lv[rt*4+rr] = linv[cjj][row];
        av[rt*4+rr] = afin[cjj][row];
        tl[rt*4+rr] = twl[cjj][row];
      }
    float vtn[4];
    const float* vtN = Vtail + (size_t)(b16 + co) * 17 * 64 + nct * 64;
    #pragma unroll
    for (int ctt = 0; ctt < 4; ++ctt) vtn[ctt] = vtN[ctt*16 + n16];
    const float mwjo = mix_w[(h0 + co) * 2 + cjj];
    #pragma unroll
    for (int rt = 0; rt < 2; ++rt)
      #pragma unroll
      for (int ctt = 0; ctt < 4; ++ctt)
        #pragma unroll
        for (int rr = 0; rr < 4; ++rr)
          acc[rt][ctt][rr] = mwjo * lv[rt*4+rr] *
              (acc[rt][ctt][rr] * av[rt*4+rr] + tl[rt*4+rr] * vtn[ctt]);
    if (cjj == 0) {
      #pragma unroll
      for (int rt = 0; rt < 2; ++rt)
        #pragma unroll
        for (int ctt = 0; ctt < 4; ++ctt)
          #pragma unroll
          for (int rr = 0; rr < 4; ++rr) {
            int row = chf*32 + rt*16 + q4*4 + rr;
            Ob[(co*64 + row) * 68 + ctt*16 + n16] = acc[rt][ctt][rr];
          }
    }
  }
  __syncthreads();
  if (cjj == 1) {
    #pragma unroll
    for (int rt = 0; rt < 2; ++rt)
      #pragma unroll
      for (int ctt = 0; ctt < 4; ++ctt)
        #pragma unroll
        for (int rr = 0; rr < 4; ++rr) {
          int row = chf*32 + rt*16 + q4*4 + rr;
          Ob[(co*64 + row) * 68 + ctt*16 + n16] += acc[rt][ctt][rr];
        }
  }
  __syncthreads();

  // ---------- + mix_b*colsum, DyT, store ----------
  const float dalpha = dyt_alpha[0], dsc = depth_scale[0];
  #pragma unroll
  for (int it = 0; it < 2; ++it) {
    int c = tid + it * 512;
    int o_ = c >> 9, row = (c >> 3) & 63, dblk = (c & 7) * 8;
    int ho = h0 + o_;
    const float* ob = &Ob[(o_ * 64 + row) * 68 + dblk];
    float4 v0 = *(const float4*)ob;
    float4 v1 = *(const float4*)(ob + 4);
    const float* vt0 = Vtail + (size_t)(b16 + o_) * 17 * 64 + dblk;
    float4 t0 = *(const float4*)vt0;
    float4 t1 = *(const float4*)(vt0 + 4);
    float4 w0_ = *(const float4*)(dyt_w + dblk);
    float4 w1_ = *(const float4*)(dyt_w + dblk + 4);
    float4 d0_ = *(const float4*)(dyt_b + dblk);
    float4 d1_ = *(const float4*)(dyt_b + dblk + 4);
    float mb = mix_b[ho];
    float vv[8] = {v0.x + mb*t0.x, v0.y + mb*t0.y, v0.z + mb*t0.z, v0.w + mb*t0.w,
                   v1.x + mb*t1.x, v1.y + mb*t1.y, v1.z + mb*t1.z, v1.w + mb*t1.w};
    float wv[8] = {w0_.x, w0_.y, w0_.z, w0_.w, w1_.x, w1_.y, w1_.z, w1_.w};
    float dv[8] = {d0_.x, d0_.y, d0_.z, d0_.w, d1_.x, d1_.y, d1_.z, d1_.w};
    unsigned int pk[4];
    #pragma unroll
    for (int e = 0; e < 4; ++e) {
      float e0 = __expf(2.f * dalpha * vv[2*e]);
      float e1 = __expf(2.f * dalpha * vv[2*e+1]);
      float y0 = ((1.f - 2.f / (e0 + 1.f)) * wv[2*e]   + dv[2*e])   * dsc;
      float y1 = ((1.f - 2.f / (e1 + 1.f)) * wv[2*e+1] + dv[2*e+1]) * dsc;
      pk[e] = cvt_pk_bf16(y0, y1);
    }
    *(uint4*)(out_attn + ((size_t)(b * 1024 + q0 + row) << 10) + ho * 64 + dblk) =
        *(const uint4*)pk;
  }
}

// ---------------------------------------------------------------------------
extern "C" void kernel_launch(void* const* d_in, const int* in_sizes, int n_in,
                              void* d_out, int out_size, void* d_ws, size_t ws_size,
                              hipStream_t stream) {
  const float* Q    = (const float*)d_in[0];
  const float* Kx   = (const float*)d_in[1];
  const float* V    = (const float*)d_in[2];
  const float* Wq   = (const float*)d_in[3];
  const float* bq   = (const float*)d_in[4];
  const float* Wk   = (const float*)d_in[5];
  const float* bk   = (const float*)d_in[6];
  const float* Wv   = (const float*)d_in[7];
  const float* bv   = (const float*)d_in[8];
  const float* Wo   = (const float*)d_in[9];
  const float* bo   = (const float*)d_in[10];
  const float* kq_w = (const float*)d_in[11];
  const float* kq_b = (const float*)d_in[12];
  const float* mixw = (const float*)d_in[13];
  const float* mixb = (const float*)d_in[14];
  const float* dyta = (const float*)d_in[15];
  const float* dytw = (const float*)d_in[16];
  const float* dytb = (const float*)d_in[17];
  const float* dsc  = (const float*)d_in[18];

  char* ws = (char*)d_ws;
  bf16* qh     = (bf16*)(ws);                              // 4 MB
  bf16* kh     = (bf16*)(ws + (size_t)(4  << 20));         // 4 MB
  bf16* vT     = (bf16*)(ws + (size_t)(8  << 20));         // 4 MB
  float* Vtail = (float*)(ws + (size_t)(16 << 20));        // 136 KB
  float* Tsum  = (float*)(ws + (size_t)(16 << 20) + (256 << 10)); // 128 KB
  bf16* WtT    = (bf16*)(ws + (size_t)(17 << 20));         // 8 MB (4 planes x 2MB)
  bf16* oat    = (bf16*)(ws + (size_t)(17 << 20));         // 4 MB, aliases Wq/Wk planes (dead after proj)

  wtr_k<<<dim3(16, 16, 4), 256, 0, stream>>>(Wq, Wk, Wv, Wo, WtT);
  proj_gemm_k<<<dim3(16, 32, 3), 256, 0, stream>>>(Q, Kx, V, WtT, bq, bk, bv, qh);
  vtile_sum_k<<<dim3(16, 16, 2), 64, 0, stream>>>(vT, Tsum);
  vtail_k<<<dim3(16, 2), 64, 0, stream>>>(Tsum, Vtail);
  attn_k<<<dim3(16, 8, 2), 512, 0, stream>>>(qh, kh, vT, kq_w, kq_b, Vtail,
                                             mixw, mixb, dyta, dytw, dytb, dsc, oat);
  out_gemm_k<<<dim3(16, 32), 256, 0, stream>>>(oat, WtT + ((size_t)3 << 20), bo, (float*)d_out);
}

// Round 8
// 251.854 us; speedup vs baseline: 1.1420x; 1.1420x over previous
//
#include <hip/hip_runtime.h>
#include <cstdint>
#include <cstddef>

typedef __bf16 bf16;
typedef __bf16 bf16x8 __attribute__((ext_vector_type(8)));
typedef float f32x4 __attribute__((ext_vector_type(4)));

#define DEVI static __device__ __forceinline__

// pack two f32 -> two bf16 (RTNE) in one uint
DEVI unsigned int cvt_pk_bf16(float lo, float hi) {
  unsigned int bl = __float_as_uint(lo);
  bl += 0x7fffu + ((bl >> 16) & 1u);
  unsigned int bh = __float_as_uint(hi);
  bh += 0x7fffu + ((bh >> 16) & 1u);
  return (bl >> 16) | (bh & 0xffff0000u);
}
DEVI float bf_lo(unsigned int u) { return __uint_as_float(u << 16); }
DEVI float bf_hi(unsigned int u) { return __uint_as_float(u & 0xffff0000u); }

// ---------------------------------------------------------------------------
// W transpose prepass: W (1024x1024 f32, [k][n]) -> Wt (bf16 [n][k]).
// ---------------------------------------------------------------------------
__global__ __launch_bounds__(256) void wtr_k(
    const float* __restrict__ Wq, const float* __restrict__ Wk,
    const float* __restrict__ Wv, const float* __restrict__ Wo,
    bf16* __restrict__ Wt)
{
  const int z = blockIdx.z;
  const float* W = (z == 0) ? Wq : (z == 1) ? Wk : (z == 2) ? Wv : Wo;
  bf16* out = Wt + ((size_t)z << 20);
  const int n0 = blockIdx.x * 64, k0 = blockIdx.y * 64;
  __shared__ bf16 Ts[64 * 72];
  const int tid = threadIdx.x;
  #pragma unroll
  for (int i = 0; i < 4; ++i) {
    int t = tid + i * 256;
    int kr = t >> 4, nc = t & 15;
    float4 v = *(const float4*)(W + (size_t)(k0 + kr) * 1024 + n0 + nc * 4);
    Ts[(nc * 4 + 0) * 72 + kr] = (bf16)v.x;
    Ts[(nc * 4 + 1) * 72 + kr] = (bf16)v.y;
    Ts[(nc * 4 + 2) * 72 + kr] = (bf16)v.z;
    Ts[(nc * 4 + 3) * 72 + kr] = (bf16)v.w;
  }
  __syncthreads();
  const int n = tid >> 2, kc = tid & 3;
  *(uint4*)(out + (size_t)(n0 + n) * 1024 + k0 + kc * 16) =
      *(const uint4*)(&Ts[n * 72 + kc * 16]);
  *(uint4*)(out + (size_t)(n0 + n) * 1024 + k0 + kc * 16 + 8) =
      *(const uint4*)(&Ts[n * 72 + kc * 16 + 8]);
}

// ---------------------------------------------------------------------------
// Fused projection GEMM, f32 A staged inline to bf16, register prefetch.
// grid (16,32,3): z=0 Q->qh, z=1 K->kh (B,H,S,HD);
// z=2: V -> V2 in PV B-fragment order: per (b,h,kt):
//   V2[kk*2048 + ctt*512 + (q4*16+n16)*8 + j] = v[s=kt*64+kk*32+q4*8+j][d=ctt*16+n16]
// ---------------------------------------------------------------------------
__global__ __launch_bounds__(256) void proj_gemm_k(
    const float* __restrict__ Q, const float* __restrict__ K,
    const float* __restrict__ V, const bf16* __restrict__ Wt,
    const float* __restrict__ bq, const float* __restrict__ bk,
    const float* __restrict__ bv, bf16* __restrict__ outbase)
{
  const int z = blockIdx.z;
  const float* A = (z == 0) ? Q : (z == 1) ? K : V;
  const bf16* Bt = Wt + ((size_t)z << 20);
  const float* bias = (z == 0) ? bq : (z == 1) ? bk : bv;
  bf16* outb = outbase + ((size_t)z << 21);

  __shared__ __align__(16) char sm[10240];
  bf16* As = (bf16*)sm;
  bf16* Bs = As + 64 * 40;
  bf16* T2 = (bf16*)sm;            // [64 d][72 s] (aliases, post-loop z==2)

  const int tid = threadIdx.x, lane = tid & 63, wid = tid >> 6;
  const int q4 = lane >> 4, n16 = lane & 15;
  const int wm = wid >> 1, wn = wid & 1;
  const int m0 = blockIdx.y * 64, n0 = blockIdx.x * 64;
  const int brow = tid >> 2, bc = tid & 3;
  f32x4 acc[2][2] = {};

  float4 aR0 = *(const float4*)(A + (size_t)(m0 + brow) * 1024 + bc * 8);
  float4 aR1 = *(const float4*)(A + (size_t)(m0 + brow) * 1024 + bc * 8 + 4);
  uint4 bR = *(const uint4*)(Bt + (size_t)(n0 + brow) * 1024 + bc * 8);
  for (int kb = 0; kb < 32; ++kb) {
    __syncthreads();
    *(uint2*)(&As[brow * 40 + bc * 8]) =
        make_uint2(cvt_pk_bf16(aR0.x, aR0.y), cvt_pk_bf16(aR0.z, aR0.w));
    *(uint2*)(&As[brow * 40 + bc * 8 + 4]) =
        make_uint2(cvt_pk_bf16(aR1.x, aR1.y), cvt_pk_bf16(aR1.z, aR1.w));
    *(uint4*)(&Bs[brow * 40 + bc * 8]) = bR;
    __syncthreads();
    if (kb < 31) {
      const int k1 = (kb + 1) * 32;
      aR0 = *(const float4*)(A + (size_t)(m0 + brow) * 1024 + k1 + bc * 8);
      aR1 = *(const float4*)(A + (size_t)(m0 + brow) * 1024 + k1 + bc * 8 + 4);
      bR  = *(const uint4*)(Bt + (size_t)(n0 + brow) * 1024 + k1 + bc * 8);
    }
    bf16x8 af[2], bfv[2];
    #pragma unroll
    for (int rt = 0; rt < 2; ++rt)
      af[rt] = *(const bf16x8*)(&As[(wm * 32 + rt * 16 + n16) * 40 + q4 * 8]);
    #pragma unroll
    for (int ct = 0; ct < 2; ++ct)
      bfv[ct] = *(const bf16x8*)(&Bs[(wn * 32 + ct * 16 + n16) * 40 + q4 * 8]);
    #pragma unroll
    for (int rt = 0; rt < 2; ++rt)
      #pragma unroll
      for (int ct = 0; ct < 2; ++ct)
        acc[rt][ct] = __builtin_amdgcn_mfma_f32_16x16x32_bf16(af[rt], bfv[ct], acc[rt][ct], 0, 0, 0);
  }

  if (z < 2) {   // (B,H,S,HD)
    #pragma unroll
    for (int ct = 0; ct < 2; ++ct) {
      int col = n0 + wn * 32 + ct * 16 + n16;
      float bvl = bias[col];
      int h = col >> 6, d = col & 63;
      #pragma unroll
      for (int rt = 0; rt < 2; ++rt) {
        #pragma unroll
        for (int r = 0; r < 4; ++r) {
          int row = m0 + wm * 32 + rt * 16 + q4 * 4 + r;
          int b2 = row >> 10, s = row & 1023;
          outb[((size_t)((b2 * 16 + h) * 1024 + s) << 6) + d] =
              (bf16)(acc[rt][ct][r] + bvl);
        }
      }
    }
  } else {       // V2 fragment layout
    __syncthreads();
    #pragma unroll
    for (int ct = 0; ct < 2; ++ct) {
      int cl = wn * 32 + ct * 16 + n16;
      float bvl = bias[n0 + cl];
      #pragma unroll
      for (int rt = 0; rt < 2; ++rt)
        #pragma unroll
        for (int r = 0; r < 4; ++r) {
          int rl = wm * 32 + rt * 16 + q4 * 4 + r;
          T2[cl * 72 + rl] = (bf16)(acc[rt][ct][r] + bvl);
        }
    }
    __syncthreads();
    const int b2 = m0 >> 10, kt = (m0 & 1023) >> 6, h = n0 >> 6;
    bf16* vout = outb + ((size_t)(b2 * 16 + h) << 16) + kt * 4096;
    #pragma unroll
    for (int i = 0; i < 2; ++i) {
      int c = tid + i * 256;                 // 0..511 16B-chunks
      int kk = c >> 8, ctt = (c >> 6) & 3, q4c = (c >> 4) & 3, n16c = c & 15;
      uint4 v = *(const uint4*)(&T2[(ctt * 16 + n16c) * 72 + kk * 32 + q4c * 8]);
      *(uint4*)(vout + kk * 2048 + ctt * 512 + (q4c * 16 + n16c) * 8) = v;
    }
  }
}

// ---------------------------------------------------------------------------
// Output GEMM: d_out = oat(2048x1024 bf16) @ WoT + bo, f32 out. Prefetched.
// ---------------------------------------------------------------------------
__global__ __launch_bounds__(256) void out_gemm_k(
    const bf16* __restrict__ Ab, const bf16* __restrict__ Bt,
    const float* __restrict__ bias, float* __restrict__ outf)
{
  __shared__ __align__(16) char sm[10240];
  bf16* As = (bf16*)sm;
  bf16* Bs = As + 64 * 40;
  const int tid = threadIdx.x, lane = tid & 63, wid = tid >> 6;
  const int q4 = lane >> 4, n16 = lane & 15;
  const int wm = wid >> 1, wn = wid & 1;
  const int m0 = blockIdx.y * 64, n0 = blockIdx.x * 64;
  const int brow = tid >> 2, bc = tid & 3;
  f32x4 acc[2][2] = {};

  uint4 aR = *(const uint4*)(Ab + (size_t)(m0 + brow) * 1024 + bc * 8);
  uint4 bR = *(const uint4*)(Bt + (size_t)(n0 + brow) * 1024 + bc * 8);
  for (int kb = 0; kb < 32; ++kb) {
    __syncthreads();
    *(uint4*)(&As[brow * 40 + bc * 8]) = aR;
    *(uint4*)(&Bs[brow * 40 + bc * 8]) = bR;
    __syncthreads();
    if (kb < 31) {
      const int k1 = (kb + 1) * 32;
      aR = *(const uint4*)(Ab + (size_t)(m0 + brow) * 1024 + k1 + bc * 8);
      bR = *(const uint4*)(Bt + (size_t)(n0 + brow) * 1024 + k1 + bc * 8);
    }
    bf16x8 af[2], bfv[2];
    #pragma unroll
    for (int rt = 0; rt < 2; ++rt)
      af[rt] = *(const bf16x8*)(&As[(wm * 32 + rt * 16 + n16) * 40 + q4 * 8]);
    #pragma unroll
    for (int ct = 0; ct < 2; ++ct)
      bfv[ct] = *(const bf16x8*)(&Bs[(wn * 32 + ct * 16 + n16) * 40 + q4 * 8]);
    #pragma unroll
    for (int rt = 0; rt < 2; ++rt)
      #pragma unroll
      for (int ct = 0; ct < 2; ++ct)
        acc[rt][ct] = __builtin_amdgcn_mfma_f32_16x16x32_bf16(af[rt], bfv[ct], acc[rt][ct], 0, 0, 0);
  }
  #pragma unroll
  for (int ct = 0; ct < 2; ++ct) {
    int col = n0 + wn * 32 + ct * 16 + n16;
    float bvl = bias[col];
    #pragma unroll
    for (int rt = 0; rt < 2; ++rt)
      #pragma unroll
      for (int r = 0; r < 4; ++r) {
        int row = m0 + wm * 32 + rt * 16 + q4 * 4 + r;
        outf[(size_t)row * 1024 + col] = acc[rt][ct][r] + bvl;
      }
  }
}

// ---------------------------------------------------------------------------
// per-(b,h,ktile) column sums of v (V2 fragment layout) + suffix scan
// ---------------------------------------------------------------------------
__global__ void vtile_sum_k(const bf16* __restrict__ V2, float* __restrict__ Tsum)
{
  int kt = blockIdx.x, h = blockIdx.y, b = blockIdx.z, d = threadIdx.x;
  int ctt = d >> 4, n16c = d & 15;
  const bf16* p = V2 + ((size_t)(b * 16 + h) << 16) + kt * 4096 + ctt * 512 + n16c * 8;
  float s = 0.f;
  #pragma unroll
  for (int kk = 0; kk < 2; ++kk)
    #pragma unroll
    for (int q4i = 0; q4i < 4; ++q4i)
      #pragma unroll
      for (int j = 0; j < 8; ++j)
        s += (float)p[kk * 2048 + q4i * 128 + j];
  Tsum[((b * 16 + h) * 16 + kt) * 64 + d] = s;
}

__global__ void vtail_k(const float* __restrict__ Tsum, float* __restrict__ Vtail)
{
  int h = blockIdx.x, b = blockIdx.y, d = threadIdx.x;
  float c = 0.f;
  Vtail[((b * 16 + h) * 17 + 16) * 64 + d] = 0.f;
  for (int kt = 15; kt >= 0; --kt) {
    c += Tsum[((b * 16 + h) * 16 + kt) * 64 + d];
    Vtail[((b * 16 + h) * 17 + kt) * 64 + d] = c;
  }
}

// ---------------------------------------------------------------------------
// K2: logits + 3x3 conv -> P = exp(conv - tile_row_max) stored in PV A-frag
// order ([stripe][kk][lane][8]), plus (mxt, sumP) per tile row.
// Inputs staged through LDS with fully-coalesced loads.
// ---------------------------------------------------------------------------
__global__ __launch_bounds__(320) void logits_conv_k(
    const bf16* __restrict__ qh, const bf16* __restrict__ kh,
    const float* __restrict__ kq_w, const float* __restrict__ kq_b,
    bf16* __restrict__ conv_out, float* __restrict__ tstats)
{
  const int tt = blockIdx.x;
  int qt = 0, base = 0;
  while (qt < 15 && base + qt + 2 <= tt) { base += qt + 2; ++qt; }
  const int ct = tt - base;
  const int h = blockIdx.y, b = blockIdx.z;
  const int q0 = qt * 64, c0 = ct * 64;
  __shared__ __align__(16) bf16 Ast[80 * 72];   // q rows q0-2 .. q0+77 (clamped)
  __shared__ __align__(16) bf16 Kst[80 * 72];   // k rows c0-1 .. c0+78 (clamped)
  __shared__ float Ls[66 * 68];                 // logits halo (f32)
  const int tid = threadIdx.x;
  const int lane = tid & 63, wid = tid >> 6;    // 5 waves
  const int q4 = lane >> 4, n16 = lane & 15;
  const bf16* qb = qh + ((size_t)(b * 16 + h) << 16);
  const bf16* kb = kh + ((size_t)(b * 16 + h) << 16);

  // ---- coalesced staging (contiguous 10 KB spans) ----
  for (int t = tid; t < 640; t += 320) {
    int row = t >> 3, ch = t & 7;
    int ar = min(max(q0 - 2 + row, 0), 1023);
    *(uint4*)(&Ast[row * 72 + ch * 8]) = *(const uint4*)(qb + ar * 64 + ch * 8);
  }
  for (int t = tid; t < 640; t += 320) {
    int row = t >> 3, ch = t & 7;
    int br = min(max(c0 - 1 + row, 0), 1023);
    *(uint4*)(&Kst[row * 72 + ch * 8]) = *(const uint4*)(kb + br * 64 + ch * 8);
  }
  __syncthreads();

  // ---- QK^T from LDS frags ----
  const int arow = wid * 16 + n16;
  bf16x8 a0 = *(const bf16x8*)(&Ast[arow * 72 + q4 * 8]);
  bf16x8 a1 = *(const bf16x8*)(&Ast[arow * 72 + 32 + q4 * 8]);
  f32x4 acc[5] = {};
  #pragma unroll
  for (int c5 = 0; c5 < 5; ++c5) {
    int brow = c5 * 16 + n16;
    bf16x8 b0 = *(const bf16x8*)(&Kst[brow * 72 + q4 * 8]);
    bf16x8 b1 = *(const bf16x8*)(&Kst[brow * 72 + 32 + q4 * 8]);
    acc[c5] = __builtin_amdgcn_mfma_f32_16x16x32_bf16(a0, b0, acc[c5], 0, 0, 0);
    acc[c5] = __builtin_amdgcn_mfma_f32_16x16x32_bf16(a1, b1, acc[c5], 0, 0, 0);
  }
  #pragma unroll
  for (int c5 = 0; c5 < 5; ++c5) {
    #pragma unroll
    for (int r = 0; r < 4; ++r) {
      int Lrow = wid * 16 + q4 * 4 + r;
      int Lcol = c5 * 16 + n16;
      if (Lrow < 66 && Lcol < 66) {
        int rg = q0 - 2 + Lrow;
        int cg = c0 - 1 + Lcol;
        float v = (cg >= 0 && cg <= rg) ? acc[c5][r] * 0.125f : 0.f;
        Ls[Lrow * 68 + Lcol] = v;
      }
    }
  }
  __syncthreads();

  if (tid < 256) {
    float w9[9];
    #pragma unroll
    for (int i = 0; i < 9; ++i) w9[i] = kq_w[h * 9 + i];
    const float bb = kq_b[h];
    const size_t tplane = (size_t)(b * 16 + h) * 151 + base + ct;
    bf16* tb = conv_out + tplane * 4096;
    float2* st = (float2*)tstats + tplane * 64;

    const int r = tid >> 2, qr = tid & 3;   // output row, 16-col quarter
    float4 R0[5], R1[5], R2[5];
    const float* L0 = &Ls[r * 68 + qr * 16];
    #pragma unroll
    for (int i = 0; i < 5; ++i) {
      R0[i] = *(const float4*)(L0 + i * 4);
      R1[i] = *(const float4*)(L0 + 68 + i * 4);
      R2[i] = *(const float4*)(L0 + 136 + i * 4);
    }
    const float* f0 = (const float*)R0;
    const float* f1 = (const float*)R1;
    const float* f2 = (const float*)R2;
    float o[16];
    #pragma unroll
    for (int jj = 0; jj < 16; ++jj)
      o[jj] = bb + w9[0]*f0[jj] + w9[1]*f0[jj+1] + w9[2]*f0[jj+2]
                 + w9[3]*f1[jj] + w9[4]*f1[jj+1] + w9[5]*f1[jj+2]
                 + w9[6]*f2[jj] + w9[7]*f2[jj+1] + w9[8]*f2[jj+2];
    float mx = o[0];
    #pragma unroll
    for (int jj = 1; jj < 16; ++jj) mx = fmaxf(mx, o[jj]);
    mx = fmaxf(mx, __shfl_xor(mx, 1));
    mx = fmaxf(mx, __shfl_xor(mx, 2));
    unsigned int p[8];
    #pragma unroll
    for (int jj = 0; jj < 8; ++jj)
      p[jj] = cvt_pk_bf16(__expf(o[2*jj] - mx), __expf(o[2*jj+1] - mx));
    // store in PV A-frag order: [sr][kk][q4*16+n16][8]
    const int kk = qr >> 1, q4b = (qr & 1) * 2, sr = r >> 4, n16r = r & 15;
    *(uint4*)(tb + (sr * 2 + kk) * 512 + (q4b * 16 + n16r) * 8)       = *(const uint4*)&p[0];
    *(uint4*)(tb + (sr * 2 + kk) * 512 + ((q4b + 1) * 16 + n16r) * 8) = *(const uint4*)&p[4];
    float s = 0.f;
    #pragma unroll
    for (int jj = 0; jj < 8; ++jj) s += bf_lo(p[jj]) + bf_hi(p[jj]);
    s += __shfl_xor(s, 1);
    s += __shfl_xor(s, 2);
    if (qr == 0) st[r] = make_float2(mx, s);
  }
}

// ---------------------------------------------------------------------------
// K3a: combine per-tile stats -> per-row (max m, 1/l) incl. constant tail
// ---------------------------------------------------------------------------
__global__ __launch_bounds__(256) void combine_k(
    const float* __restrict__ tstats, const float* __restrict__ kq_b,
    float* __restrict__ rs)
{
  const int ridx = blockIdx.x * 256 + threadIdx.x;
  const int q = ridx & 1023, h = (ridx >> 10) & 15, plane = ridx >> 10;
  const int qt = q >> 6;
  const int nkt = min(qt + 2, 16);
  const int Tc = 1024 - (nkt << 6);
  const float2* ts = (const float2*)tstats +
      ((size_t)plane * 151 + (size_t)(qt * (qt + 3) / 2)) * 64 + (q & 63);
  const float kb = kq_b[h];
  float mx = (Tc > 0) ? kb : -3.0e38f;
  for (int kt = 0; kt < nkt; ++kt) mx = fmaxf(mx, ts[(size_t)kt * 64].x);
  float s = (float)Tc * __expf(kb - mx);
  for (int kt = 0; kt < nkt; ++kt) {
    float2 v = ts[(size_t)kt * 64];
    s += v.y * __expf(v.x - mx);
  }
  rs[(size_t)ridx * 2]     = mx;
  rs[(size_t)ridx * 2 + 1] = 1.f / s;
}

// ---------------------------------------------------------------------------
// K3b: PV from fragment-ordered P and V2 — every load 64-lane contiguous.
// A_o = sum_j (mw[o,j]*rinv_j*exp(mxt_j-m_j))*P_j
// ---------------------------------------------------------------------------
__global__ __launch_bounds__(256) void pv_k(
    const bf16* __restrict__ conv_out, const bf16* __restrict__ V2,
    const float* __restrict__ rs, const float* __restrict__ tstats,
    const float* __restrict__ Vtail,
    const float* __restrict__ mix_w, const float* __restrict__ mix_b,
    const float* __restrict__ kq_b,
    const float* __restrict__ dyt_alpha, const float* __restrict__ dyt_w,
    const float* __restrict__ dyt_b, const float* __restrict__ depth_scale,
    bf16* __restrict__ out_attn)
{
  const int qt16 = blockIdx.x, g = blockIdx.y, b = blockIdx.z;
  const int qt = qt16 >> 2;
  const int nkt = min(qt + 2, 16);
  const int Tc = 1024 - (nkt << 6);
  const int tid = threadIdx.x, lane = tid & 63, wid = tid >> 6;
  const int q4 = lane >> 4, n16 = lane & 15;
  const int oo = wid >> 1, kh = wid & 1;
  const int h0 = 2 * g, ho = h0 + oo;
  const int sr = qt16 & 3, strow = sr * 16;
  const size_t tbase = (size_t)(qt * (qt + 3) / 2);

  const int qrow = qt16 * 16 + n16;
  const float2 r0 = *(const float2*)(rs + ((((size_t)(b * 16 + h0)     << 10) + qrow) << 1));
  const float2 r1 = *(const float2*)(rs + ((((size_t)(b * 16 + h0 + 1) << 10) + qrow) << 1));
  const float m0 = r0.x, m1 = r1.x;
  const float mwa = mix_w[ho * 2 + 0], mwb = mix_w[ho * 2 + 1];
  const float wa = mwa * r0.y, wb = mwb * r1.y;   // mw * rinv

  const bf16* pb0 = conv_out +
      ((size_t)(b * 16 + h0) * 151 + tbase) * 4096 + sr * 1024 + lane * 8;
  const bf16* pb1 = pb0 + (size_t)151 * 4096;
  const float2* ts0 = (const float2*)tstats +
      ((size_t)(b * 16 + h0) * 151 + tbase) * 64 + strow + n16;
  const float2* ts1 = ts0 + (size_t)151 * 64;
  const bf16* vb = V2 + ((size_t)(b * 16 + ho) << 16) + lane * 8;

  const int niter = (nkt - kh + 1) >> 1;
  float wk0[8], wk1[8];
  #pragma unroll
  for (int i = 0; i < 8; ++i) {
    int ktc = (i < niter) ? (kh + 2 * i) : 0;
    wk0[i] = wa * __expf(ts0[(size_t)ktc * 64].x - m0);
    wk1[i] = wb * __expf(ts1[(size_t)ktc * 64].x - m1);
  }

  f32x4 acc[4] = {};
  int ii = 0;
  for (int kt = kh; kt < nkt; kt += 2, ++ii) {
    uint4 u0[2], u1[2];
    #pragma unroll
    for (int kk = 0; kk < 2; ++kk) {
      u0[kk] = *(const uint4*)(pb0 + (size_t)kt * 4096 + kk * 512);
      u1[kk] = *(const uint4*)(pb1 + (size_t)kt * 4096 + kk * 512);
    }
    bf16x8 bv[2][4];
    #pragma unroll
    for (int kk = 0; kk < 2; ++kk)
      #pragma unroll
      for (int ctt = 0; ctt < 4; ++ctt)
        bv[kk][ctt] = *(const bf16x8*)(vb + (size_t)kt * 4096 + kk * 2048 + ctt * 512);
    const float w0 = wk0[ii], w1 = wk1[ii];
    #pragma unroll
    for (int kk = 0; kk < 2; ++kk) {
      bf16x8 af;
      const unsigned int* a0p = (const unsigned int*)&u0[kk];
      const unsigned int* a1p = (const unsigned int*)&u1[kk];
      #pragma unroll
      for (int i2 = 0; i2 < 4; ++i2) {
        float a0 = w0 * bf_lo(a0p[i2]) + w1 * bf_lo(a1p[i2]);
        float a1 = w0 * bf_hi(a0p[i2]) + w1 * bf_hi(a1p[i2]);
        ((unsigned int*)&af)[i2] = cvt_pk_bf16(a0, a1);
      }
      #pragma unroll
      for (int ctt = 0; ctt < 4; ++ctt)
        acc[ctt] = __builtin_amdgcn_mfma_f32_16x16x32_bf16(af, bv[kk][ctt], acc[ctt], 0, 0, 0);
    }
  }

  __shared__ float Pp[2][16][64];
  if (kh == 1) {
    #pragma unroll
    for (int ctt = 0; ctt < 4; ++ctt)
      #pragma unroll
      for (int r = 0; r < 4; ++r)
        Pp[oo][q4 * 4 + r][ctt * 16 + n16] = acc[ctt][r];
  }
  __syncthreads();
  if (kh == 1) return;
  #pragma unroll
  for (int ctt = 0; ctt < 4; ++ctt)
    #pragma unroll
    for (int r = 0; r < 4; ++r)
      acc[ctt][r] += Pp[oo][q4 * 4 + r][ctt * 16 + n16];

  const float kqb0 = kq_b[h0], kqb1 = kq_b[h0 + 1];
  float tw[4];
  #pragma unroll
  for (int r = 0; r < 4; ++r) {
    int qr = qt16 * 16 + q4 * 4 + r;
    float2 s0 = *(const float2*)(rs + ((((size_t)(b * 16 + h0)     << 10) + qr) << 1));
    float2 s1 = *(const float2*)(rs + ((((size_t)(b * 16 + h0 + 1) << 10) + qr) << 1));
    tw[r] = (Tc > 0) ? (mwa * s0.y * __expf(kqb0 - s0.x) +
                        mwb * s1.y * __expf(kqb1 - s1.x)) : 0.f;
  }
  const float mb = mix_b[ho];
  const float alpha = dyt_alpha[0], dsc = depth_scale[0];
  const float* vt = Vtail + (size_t)(b * 16 + ho) * 17 * 64;
  #pragma unroll
  for (int ctt = 0; ctt < 4; ++ctt) {
    int d = ctt * 16 + n16;
    float vtn = vt[(size_t)nkt * 64 + d];
    float vt0 = vt[d];
    float wgt = dyt_w[d], bds = dyt_b[d];
    #pragma unroll
    for (int r = 0; r < 4; ++r) {
      float v = acc[ctt][r] + tw[r] * vtn + mb * vt0;
      float e = __expf(2.f * alpha * v);
      float th = 1.f - 2.f / (e + 1.f);
      float y = (th * wgt + bds) * dsc;
      int qr = qt16 * 16 + q4 * 4 + r;
      out_attn[(((size_t)(b * 1024 + qr)) << 10) + ho * 64 + d] = (bf16)y;
    }
  }
}

// ---------------------------------------------------------------------------
extern "C" void kernel_launch(void* const* d_in, const int* in_sizes, int n_in,
                              void* d_out, int out_size, void* d_ws, size_t ws_size,
                              hipStream_t stream) {
  const float* Q    = (const float*)d_in[0];
  const float* Kx   = (const float*)d_in[1];
  const float* V    = (const float*)d_in[2];
  const float* Wq   = (const float*)d_in[3];
  const float* bq   = (const float*)d_in[4];
  const float* Wk   = (const float*)d_in[5];
  const float* bk   = (const float*)d_in[6];
  const float* Wv   = (const float*)d_in[7];
  const float* bv   = (const float*)d_in[8];
  const float* Wo   = (const float*)d_in[9];
  const float* bo   = (const float*)d_in[10];
  const float* kq_w = (const float*)d_in[11];
  const float* kq_b = (const float*)d_in[12];
  const float* mixw = (const float*)d_in[13];
  const float* mixb = (const float*)d_in[14];
  const float* dyta = (const float*)d_in[15];
  const float* dytw = (const float*)d_in[16];
  const float* dytb = (const float*)d_in[17];
  const float* dsc  = (const float*)d_in[18];

  char* ws = (char*)d_ws;
  bf16* qh     = (bf16*)(ws);                              // 4 MB (kh, V2 follow)
  float* tstat = (float*)(ws + (size_t)(12 << 20));        // 2.42 MB (alive thru pv)
  float* Vtail = (float*)(ws + (size_t)(16 << 20));        // 136 KB
  float* Tsum  = (float*)(ws + (size_t)(16 << 20) + (256 << 10)); // 128 KB
  float* rsbuf = (float*)(ws + (size_t)(16 << 20) + (512 << 10)); // 256 KB
  bf16* WtT    = (bf16*)(ws + (size_t)(17 << 20));         // 8 MB (4 planes x 2MB)
  bf16* oat    = (bf16*)(ws + (size_t)(17 << 20));         // 4 MB, aliases Wq/Wk planes
  bf16* conv   = (bf16*)(ws + (size_t)(25 << 20));         // 39.58 MB (P2 tiles)
  bf16* kh     = qh + ((size_t)1 << 21);
  bf16* V2     = qh + ((size_t)2 << 21);

  wtr_k<<<dim3(16, 16, 4), 256, 0, stream>>>(Wq, Wk, Wv, Wo, WtT);
  proj_gemm_k<<<dim3(16, 32, 3), 256, 0, stream>>>(Q, Kx, V, WtT, bq, bk, bv, qh);
  vtile_sum_k<<<dim3(16, 16, 2), 64, 0, stream>>>(V2, Tsum);
  vtail_k<<<dim3(16, 2), 64, 0, stream>>>(Tsum, Vtail);
  logits_conv_k<<<dim3(151, 16, 2), 320, 0, stream>>>(qh, kh, kq_w, kq_b, conv, tstat);
  combine_k<<<dim3(128), 256, 0, stream>>>(tstat, kq_b, rsbuf);
  pv_k<<<dim3(64, 8, 2), 256, 0, stream>>>(conv, V2, rsbuf, tstat, Vtail, mixw, mixb, kq_b,
                                           dyta, dytw, dytb, dsc, oat);
  out_gemm_k<<<dim3(16, 32), 256, 0, stream>>>(oat, WtT + ((size_t)3 << 20), bo, (float*)d_out);
}

// Round 9
// 227.384 us; speedup vs baseline: 1.2649x; 1.1076x over previous
//
#include <hip/hip_runtime.h>
#include <cstdint>
#include <cstddef>

typedef __bf16 bf16;
typedef __bf16 bf16x8 __attribute__((ext_vector_type(8)));
typedef float f32x4 __attribute__((ext_vector_type(4)));

#define DEVI static __device__ __forceinline__

// pack two f32 -> two bf16 (RTNE) in one uint
DEVI unsigned int cvt_pk_bf16(float lo, float hi) {
  unsigned int bl = __float_as_uint(lo);
  bl += 0x7fffu + ((bl >> 16) & 1u);
  unsigned int bh = __float_as_uint(hi);
  bh += 0x7fffu + ((bh >> 16) & 1u);
  return (bl >> 16) | (bh & 0xffff0000u);
}
DEVI float bf_lo(unsigned int u) { return __uint_as_float(u << 16); }
DEVI float bf_hi(unsigned int u) { return __uint_as_float(u & 0xffff0000u); }

// ---------------------------------------------------------------------------
// W transpose prepass: W (1024x1024 f32, [k][n]) -> Wt (bf16 [n][k]).
// ---------------------------------------------------------------------------
__global__ __launch_bounds__(256) void wtr_k(
    const float* __restrict__ Wq, const float* __restrict__ Wk,
    const float* __restrict__ Wv, const float* __restrict__ Wo,
    bf16* __restrict__ Wt)
{
  const int z = blockIdx.z;
  const float* W = (z == 0) ? Wq : (z == 1) ? Wk : (z == 2) ? Wv : Wo;
  bf16* out = Wt + ((size_t)z << 20);
  const int n0 = blockIdx.x * 64, k0 = blockIdx.y * 64;
  __shared__ bf16 Ts[64 * 72];
  const int tid = threadIdx.x;
  #pragma unroll
  for (int i = 0; i < 4; ++i) {
    int t = tid + i * 256;
    int kr = t >> 4, nc = t & 15;
    float4 v = *(const float4*)(W + (size_t)(k0 + kr) * 1024 + n0 + nc * 4);
    Ts[(nc * 4 + 0) * 72 + kr] = (bf16)v.x;
    Ts[(nc * 4 + 1) * 72 + kr] = (bf16)v.y;
    Ts[(nc * 4 + 2) * 72 + kr] = (bf16)v.z;
    Ts[(nc * 4 + 3) * 72 + kr] = (bf16)v.w;
  }
  __syncthreads();
  const int n = tid >> 2, kc = tid & 3;
  *(uint4*)(out + (size_t)(n0 + n) * 1024 + k0 + kc * 16) =
      *(const uint4*)(&Ts[n * 72 + kc * 16]);
  *(uint4*)(out + (size_t)(n0 + n) * 1024 + k0 + kc * 16 + 8) =
      *(const uint4*)(&Ts[n * 72 + kc * 16 + 8]);
}

// ---------------------------------------------------------------------------
// Fused projection GEMM, f32 A staged inline to bf16, register prefetch.
// grid (16,32,3): z=0 Q->qh, z=1 K->kh (B,H,S,HD);
// z=2: V -> V2 in PV B-fragment order: per (b,h,kt):
//   V2[kk*2048 + ctt*512 + (q4*16+n16)*8 + j] = v[s=kt*64+kk*32+q4*8+j][d=ctt*16+n16]
// ---------------------------------------------------------------------------
__global__ __launch_bounds__(256) void proj_gemm_k(
    const float* __restrict__ Q, const float* __restrict__ K,
    const float* __restrict__ V, const bf16* __restrict__ Wt,
    const float* __restrict__ bq, const float* __restrict__ bk,
    const float* __restrict__ bv, bf16* __restrict__ outbase)
{
  const int z = blockIdx.z;
  const float* A = (z == 0) ? Q : (z == 1) ? K : V;
  const bf16* Bt = Wt + ((size_t)z << 20);
  const float* bias = (z == 0) ? bq : (z == 1) ? bk : bv;
  bf16* outb = outbase + ((size_t)z << 21);

  __shared__ __align__(16) char sm[10240];
  bf16* As = (bf16*)sm;
  bf16* Bs = As + 64 * 40;
  bf16* T2 = (bf16*)sm;            // [64 d][72 s] (aliases, post-loop z==2)

  const int tid = threadIdx.x, lane = tid & 63, wid = tid >> 6;
  const int q4 = lane >> 4, n16 = lane & 15;
  const int wm = wid >> 1, wn = wid & 1;
  const int m0 = blockIdx.y * 64, n0 = blockIdx.x * 64;
  const int brow = tid >> 2, bc = tid & 3;
  f32x4 acc[2][2] = {};

  float4 aR0 = *(const float4*)(A + (size_t)(m0 + brow) * 1024 + bc * 8);
  float4 aR1 = *(const float4*)(A + (size_t)(m0 + brow) * 1024 + bc * 8 + 4);
  uint4 bR = *(const uint4*)(Bt + (size_t)(n0 + brow) * 1024 + bc * 8);
  for (int kb = 0; kb < 32; ++kb) {
    __syncthreads();
    *(uint2*)(&As[brow * 40 + bc * 8]) =
        make_uint2(cvt_pk_bf16(aR0.x, aR0.y), cvt_pk_bf16(aR0.z, aR0.w));
    *(uint2*)(&As[brow * 40 + bc * 8 + 4]) =
        make_uint2(cvt_pk_bf16(aR1.x, aR1.y), cvt_pk_bf16(aR1.z, aR1.w));
    *(uint4*)(&Bs[brow * 40 + bc * 8]) = bR;
    __syncthreads();
    if (kb < 31) {
      const int k1 = (kb + 1) * 32;
      aR0 = *(const float4*)(A + (size_t)(m0 + brow) * 1024 + k1 + bc * 8);
      aR1 = *(const float4*)(A + (size_t)(m0 + brow) * 1024 + k1 + bc * 8 + 4);
      bR  = *(const uint4*)(Bt + (size_t)(n0 + brow) * 1024 + k1 + bc * 8);
    }
    bf16x8 af[2], bfv[2];
    #pragma unroll
    for (int rt = 0; rt < 2; ++rt)
      af[rt] = *(const bf16x8*)(&As[(wm * 32 + rt * 16 + n16) * 40 + q4 * 8]);
    #pragma unroll
    for (int ct = 0; ct < 2; ++ct)
      bfv[ct] = *(const bf16x8*)(&Bs[(wn * 32 + ct * 16 + n16) * 40 + q4 * 8]);
    #pragma unroll
    for (int rt = 0; rt < 2; ++rt)
      #pragma unroll
      for (int ct = 0; ct < 2; ++ct)
        acc[rt][ct] = __builtin_amdgcn_mfma_f32_16x16x32_bf16(af[rt], bfv[ct], acc[rt][ct], 0, 0, 0);
  }

  if (z < 2) {   // (B,H,S,HD)
    #pragma unroll
    for (int ct = 0; ct < 2; ++ct) {
      int col = n0 + wn * 32 + ct * 16 + n16;
      float bvl = bias[col];
      int h = col >> 6, d = col & 63;
      #pragma unroll
      for (int rt = 0; rt < 2; ++rt) {
        #pragma unroll
        for (int r = 0; r < 4; ++r) {
          int row = m0 + wm * 32 + rt * 16 + q4 * 4 + r;
          int b2 = row >> 10, s = row & 1023;
          outb[((size_t)((b2 * 16 + h) * 1024 + s) << 6) + d] =
              (bf16)(acc[rt][ct][r] + bvl);
        }
      }
    }
  } else {       // V2 fragment layout
    __syncthreads();
    #pragma unroll
    for (int ct = 0; ct < 2; ++ct) {
      int cl = wn * 32 + ct * 16 + n16;
      float bvl = bias[n0 + cl];
      #pragma unroll
      for (int rt = 0; rt < 2; ++rt)
        #pragma unroll
        for (int r = 0; r < 4; ++r) {
          int rl = wm * 32 + rt * 16 + q4 * 4 + r;
          T2[cl * 72 + rl] = (bf16)(acc[rt][ct][r] + bvl);
        }
    }
    __syncthreads();
    const int b2 = m0 >> 10, kt = (m0 & 1023) >> 6, h = n0 >> 6;
    bf16* vout = outb + ((size_t)(b2 * 16 + h) << 16) + kt * 4096;
    #pragma unroll
    for (int i = 0; i < 2; ++i) {
      int c = tid + i * 256;                 // 0..511 16B-chunks
      int kk = c >> 8, ctt = (c >> 6) & 3, q4c = (c >> 4) & 3, n16c = c & 15;
      uint4 v = *(const uint4*)(&T2[(ctt * 16 + n16c) * 72 + kk * 32 + q4c * 8]);
      *(uint4*)(vout + kk * 2048 + ctt * 512 + (q4c * 16 + n16c) * 8) = v;
    }
  }
}

// ---------------------------------------------------------------------------
// Output GEMM: d_out = oat(2048x1024 bf16) @ WoT + bo, f32 out. Prefetched.
// ---------------------------------------------------------------------------
__global__ __launch_bounds__(256) void out_gemm_k(
    const bf16* __restrict__ Ab, const bf16* __restrict__ Bt,
    const float* __restrict__ bias, float* __restrict__ outf)
{
  __shared__ __align__(16) char sm[10240];
  bf16* As = (bf16*)sm;
  bf16* Bs = As + 64 * 40;
  const int tid = threadIdx.x, lane = tid & 63, wid = tid >> 6;
  const int q4 = lane >> 4, n16 = lane & 15;
  const int wm = wid >> 1, wn = wid & 1;
  const int m0 = blockIdx.y * 64, n0 = blockIdx.x * 64;
  const int brow = tid >> 2, bc = tid & 3;
  f32x4 acc[2][2] = {};

  uint4 aR = *(const uint4*)(Ab + (size_t)(m0 + brow) * 1024 + bc * 8);
  uint4 bR = *(const uint4*)(Bt + (size_t)(n0 + brow) * 1024 + bc * 8);
  for (int kb = 0; kb < 32; ++kb) {
    __syncthreads();
    *(uint4*)(&As[brow * 40 + bc * 8]) = aR;
    *(uint4*)(&Bs[brow * 40 + bc * 8]) = bR;
    __syncthreads();
    if (kb < 31) {
      const int k1 = (kb + 1) * 32;
      aR = *(const uint4*)(Ab + (size_t)(m0 + brow) * 1024 + k1 + bc * 8);
      bR = *(const uint4*)(Bt + (size_t)(n0 + brow) * 1024 + k1 + bc * 8);
    }
    bf16x8 af[2], bfv[2];
    #pragma unroll
    for (int rt = 0; rt < 2; ++rt)
      af[rt] = *(const bf16x8*)(&As[(wm * 32 + rt * 16 + n16) * 40 + q4 * 8]);
    #pragma unroll
    for (int ct = 0; ct < 2; ++ct)
      bfv[ct] = *(const bf16x8*)(&Bs[(wn * 32 + ct * 16 + n16) * 40 + q4 * 8]);
    #pragma unroll
    for (int rt = 0; rt < 2; ++rt)
      #pragma unroll
      for (int ct = 0; ct < 2; ++ct)
        acc[rt][ct] = __builtin_amdgcn_mfma_f32_16x16x32_bf16(af[rt], bfv[ct], acc[rt][ct], 0, 0, 0);
  }
  #pragma unroll
  for (int ct = 0; ct < 2; ++ct) {
    int col = n0 + wn * 32 + ct * 16 + n16;
    float bvl = bias[col];
    #pragma unroll
    for (int rt = 0; rt < 2; ++rt)
      #pragma unroll
      for (int r = 0; r < 4; ++r) {
        int row = m0 + wm * 32 + rt * 16 + q4 * 4 + r;
        outf[(size_t)row * 1024 + col] = acc[rt][ct][r] + bvl;
      }
  }
}

// ---------------------------------------------------------------------------
// per-(b,h,ktile) column sums of v (V2 fragment layout) + suffix scan
// ---------------------------------------------------------------------------
__global__ void vtile_sum_k(const bf16* __restrict__ V2, float* __restrict__ Tsum)
{
  int kt = blockIdx.x, h = blockIdx.y, b = blockIdx.z, d = threadIdx.x;
  int ctt = d >> 4, n16c = d & 15;
  const bf16* p = V2 + ((size_t)(b * 16 + h) << 16) + kt * 4096 + ctt * 512 + n16c * 8;
  float s = 0.f;
  #pragma unroll
  for (int kk = 0; kk < 2; ++kk)
    #pragma unroll
    for (int q4i = 0; q4i < 4; ++q4i)
      #pragma unroll
      for (int j = 0; j < 8; ++j)
        s += (float)p[kk * 2048 + q4i * 128 + j];
  Tsum[((b * 16 + h) * 16 + kt) * 64 + d] = s;
}

__global__ void vtail_k(const float* __restrict__ Tsum, float* __restrict__ Vtail)
{
  int h = blockIdx.x, b = blockIdx.y, d = threadIdx.x;
  float c = 0.f;
  Vtail[((b * 16 + h) * 17 + 16) * 64 + d] = 0.f;
  for (int kt = 15; kt >= 0; --kt) {
    c += Tsum[((b * 16 + h) * 16 + kt) * 64 + d];
    Vtail[((b * 16 + h) * 17 + kt) * 64 + d] = c;
  }
}

// ---------------------------------------------------------------------------
// K2: logits + 3x3 conv -> P = exp(conv - tile_row_max) stored in PV A-frag
// order, plus (mxt, sumP) per tile row.
// LDS: Kst (11.5 KB, staging) UNIONED with Ls (18 KB, logits halo) — disjoint
// lifetimes, 18.4 KB total -> 6 blocks/CU (vs 3 at 41.5 KB). A-fragments load
// directly from global (2 per wave) and overlap the K staging.
// ---------------------------------------------------------------------------
__global__ __launch_bounds__(320) void logits_conv_k(
    const bf16* __restrict__ qh, const bf16* __restrict__ kh,
    const float* __restrict__ kq_w, const float* __restrict__ kq_b,
    bf16* __restrict__ conv_out, float* __restrict__ tstats)
{
  const int tt = blockIdx.x;
  int qt = 0, base = 0;
  while (qt < 15 && base + qt + 2 <= tt) { base += qt + 2; ++qt; }
  const int ct = tt - base;
  const int h = blockIdx.y, b = blockIdx.z;
  const int q0 = qt * 64, c0 = ct * 64;
  __shared__ __align__(16) char un[18432];      // union: Kst then Ls
  bf16* Kst = (bf16*)un;                        // [80][72] bf16, staging
  float* Ls = (float*)un;                       // [66][68] f32, logits halo
  const int tid = threadIdx.x;
  const int lane = tid & 63, wid = tid >> 6;    // 5 waves
  const int q4 = lane >> 4, n16 = lane & 15;
  const bf16* qb = qh + ((size_t)(b * 16 + h) << 16);
  const bf16* kb = kh + ((size_t)(b * 16 + h) << 16);

  // ---- A-fragments straight from global (issue first, overlap staging) ----
  const int ar = min(max(q0 - 2 + wid * 16 + n16, 0), 1023);
  bf16x8 a0 = *(const bf16x8*)(qb + ar * 64 + q4 * 8);
  bf16x8 a1 = *(const bf16x8*)(qb + ar * 64 + 32 + q4 * 8);

  // ---- coalesced K staging (contiguous 10 KB span) ----
  for (int t = tid; t < 640; t += 320) {
    int row = t >> 3, ch = t & 7;
    int br = min(max(c0 - 1 + row, 0), 1023);
    *(uint4*)(&Kst[row * 72 + ch * 8]) = *(const uint4*)(kb + br * 64 + ch * 8);
  }
  __syncthreads();

  // ---- QK^T (B-frags from LDS) ----
  f32x4 acc[5] = {};
  #pragma unroll
  for (int c5 = 0; c5 < 5; ++c5) {
    int brow = c5 * 16 + n16;
    bf16x8 b0 = *(const bf16x8*)(&Kst[brow * 72 + q4 * 8]);
    bf16x8 b1 = *(const bf16x8*)(&Kst[brow * 72 + 32 + q4 * 8]);
    acc[c5] = __builtin_amdgcn_mfma_f32_16x16x32_bf16(a0, b0, acc[c5], 0, 0, 0);
    acc[c5] = __builtin_amdgcn_mfma_f32_16x16x32_bf16(a1, b1, acc[c5], 0, 0, 0);
  }
  __syncthreads();   // Kst reads complete before Ls overwrites the union

  #pragma unroll
  for (int c5 = 0; c5 < 5; ++c5) {
    #pragma unroll
    for (int r = 0; r < 4; ++r) {
      int Lrow = wid * 16 + q4 * 4 + r;
      int Lcol = c5 * 16 + n16;
      if (Lrow < 66 && Lcol < 66) {
        int rg = q0 - 2 + Lrow;
        int cg = c0 - 1 + Lcol;
        float v = (cg >= 0 && cg <= rg) ? acc[c5][r] * 0.125f : 0.f;
        Ls[Lrow * 68 + Lcol] = v;
      }
    }
  }
  __syncthreads();

  if (tid < 256) {
    float w9[9];
    #pragma unroll
    for (int i = 0; i < 9; ++i) w9[i] = kq_w[h * 9 + i];
    const float bb = kq_b[h];
    const size_t tplane = (size_t)(b * 16 + h) * 151 + base + ct;
    bf16* tb = conv_out + tplane * 4096;
    float2* st = (float2*)tstats + tplane * 64;

    const int r = tid >> 2, qr = tid & 3;   // output row, 16-col quarter
    float4 R0[5], R1[5], R2[5];
    const float* L0 = &Ls[r * 68 + qr * 16];
    #pragma unroll
    for (int i = 0; i < 5; ++i) {
      R0[i] = *(const float4*)(L0 + i * 4);
      R1[i] = *(const float4*)(L0 + 68 + i * 4);
      R2[i] = *(const float4*)(L0 + 136 + i * 4);
    }
    const float* f0 = (const float*)R0;
    const float* f1 = (const float*)R1;
    const float* f2 = (const float*)R2;
    float o[16];
    #pragma unroll
    for (int jj = 0; jj < 16; ++jj)
      o[jj] = bb + w9[0]*f0[jj] + w9[1]*f0[jj+1] + w9[2]*f0[jj+2]
                 + w9[3]*f1[jj] + w9[4]*f1[jj+1] + w9[5]*f1[jj+2]
                 + w9[6]*f2[jj] + w9[7]*f2[jj+1] + w9[8]*f2[jj+2];
    float mx = o[0];
    #pragma unroll
    for (int jj = 1; jj < 16; ++jj) mx = fmaxf(mx, o[jj]);
    mx = fmaxf(mx, __shfl_xor(mx, 1));
    mx = fmaxf(mx, __shfl_xor(mx, 2));
    unsigned int p[8];
    #pragma unroll
    for (int jj = 0; jj < 8; ++jj)
      p[jj] = cvt_pk_bf16(__expf(o[2*jj] - mx), __expf(o[2*jj+1] - mx));
    // store in PV A-frag order: [sr][kk][q4*16+n16][8]
    const int kk = qr >> 1, q4b = (qr & 1) * 2, sr = r >> 4, n16r = r & 15;
    *(uint4*)(tb + (sr * 2 + kk) * 512 + (q4b * 16 + n16r) * 8)       = *(const uint4*)&p[0];
    *(uint4*)(tb + (sr * 2 + kk) * 512 + ((q4b + 1) * 16 + n16r) * 8) = *(const uint4*)&p[4];
    float s = 0.f;
    #pragma unroll
    for (int jj = 0; jj < 8; ++jj) s += bf_lo(p[jj]) + bf_hi(p[jj]);
    s += __shfl_xor(s, 1);
    s += __shfl_xor(s, 2);
    if (qr == 0) st[r] = make_float2(mx, s);
  }
}

// ---------------------------------------------------------------------------
// K3a: combine per-tile stats -> per-row (max m, 1/l) incl. constant tail
// ---------------------------------------------------------------------------
__global__ __launch_bounds__(256) void combine_k(
    const float* __restrict__ tstats, const float* __restrict__ kq_b,
    float* __restrict__ rs)
{
  const int ridx = blockIdx.x * 256 + threadIdx.x;
  const int q = ridx & 1023, h = (ridx >> 10) & 15, plane = ridx >> 10;
  const int qt = q >> 6;
  const int nkt = min(qt + 2, 16);
  const int Tc = 1024 - (nkt << 6);
  const float2* ts = (const float2*)tstats +
      ((size_t)plane * 151 + (size_t)(qt * (qt + 3) / 2)) * 64 + (q & 63);
  const float kb = kq_b[h];
  float mx = (Tc > 0) ? kb : -3.0e38f;
  for (int kt = 0; kt < nkt; ++kt) mx = fmaxf(mx, ts[(size_t)kt * 64].x);
  float s = (float)Tc * __expf(kb - mx);
  for (int kt = 0; kt < nkt; ++kt) {
    float2 v = ts[(size_t)kt * 64];
    s += v.y * __expf(v.x - mx);
  }
  rs[(size_t)ridx * 2]     = mx;
  rs[(size_t)ridx * 2 + 1] = 1.f / s;
}

// ---------------------------------------------------------------------------
// K3b: PV from fragment-ordered P and V2 — every load 64-lane contiguous.
// A_o = sum_j (mw[o,j]*rinv_j*exp(mxt_j-m_j))*P_j
// ---------------------------------------------------------------------------
__global__ __launch_bounds__(256) void pv_k(
    const bf16* __restrict__ conv_out, const bf16* __restrict__ V2,
    const float* __restrict__ rs, const float* __restrict__ tstats,
    const float* __restrict__ Vtail,
    const float* __restrict__ mix_w, const float* __restrict__ mix_b,
    const float* __restrict__ kq_b,
    const float* __restrict__ dyt_alpha, const float* __restrict__ dyt_w,
    const float* __restrict__ dyt_b, const float* __restrict__ depth_scale,
    bf16* __restrict__ out_attn)
{
  const int qt16 = blockIdx.x, g = blockIdx.y, b = blockIdx.z;
  const int qt = qt16 >> 2;
  const int nkt = min(qt + 2, 16);
  const int Tc = 1024 - (nkt << 6);
  const int tid = threadIdx.x, lane = tid & 63, wid = tid >> 6;
  const int q4 = lane >> 4, n16 = lane & 15;
  const int oo = wid >> 1, kh = wid & 1;
  const int h0 = 2 * g, ho = h0 + oo;
  const int sr = qt16 & 3, strow = sr * 16;
  const size_t tbase = (size_t)(qt * (qt + 3) / 2);

  const int qrow = qt16 * 16 + n16;
  const float2 r0 = *(const float2*)(rs + ((((size_t)(b * 16 + h0)     << 10) + qrow) << 1));
  const float2 r1 = *(const float2*)(rs + ((((size_t)(b * 16 + h0 + 1) << 10) + qrow) << 1));
  const float m0 = r0.x, m1 = r1.x;
  const float mwa = mix_w[ho * 2 + 0], mwb = mix_w[ho * 2 + 1];
  const float wa = mwa * r0.y, wb = mwb * r1.y;   // mw * rinv

  const bf16* pb0 = conv_out +
      ((size_t)(b * 16 + h0) * 151 + tbase) * 4096 + sr * 1024 + lane * 8;
  const bf16* pb1 = pb0 + (size_t)151 * 4096;
  const float2* ts0 = (const float2*)tstats +
      ((size_t)(b * 16 + h0) * 151 + tbase) * 64 + strow + n16;
  const float2* ts1 = ts0 + (size_t)151 * 64;
  const bf16* vb = V2 + ((size_t)(b * 16 + ho) << 16) + lane * 8;

  const int niter = (nkt - kh + 1) >> 1;
  float wk0[8], wk1[8];
  #pragma unroll
  for (int i = 0; i < 8; ++i) {
    int ktc = (i < niter) ? (kh + 2 * i) : 0;
    wk0[i] = wa * __expf(ts0[(size_t)ktc * 64].x - m0);
    wk1[i] = wb * __expf(ts1[(size_t)ktc * 64].x - m1);
  }

  f32x4 acc[4] = {};
  int ii = 0;
  for (int kt = kh; kt < nkt; kt += 2, ++ii) {
    uint4 u0[2], u1[2];
    #pragma unroll
    for (int kk = 0; kk < 2; ++kk) {
      u0[kk] = *(const uint4*)(pb0 + (size_t)kt * 4096 + kk * 512);
      u1[kk] = *(const uint4*)(pb1 + (size_t)kt * 4096 + kk * 512);
    }
    bf16x8 bv[2][4];
    #pragma unroll
    for (int kk = 0; kk < 2; ++kk)
      #pragma unroll
      for (int ctt = 0; ctt < 4; ++ctt)
        bv[kk][ctt] = *(const bf16x8*)(vb + (size_t)kt * 4096 + kk * 2048 + ctt * 512);
    const float w0 = wk0[ii], w1 = wk1[ii];
    #pragma unroll
    for (int kk = 0; kk < 2; ++kk) {
      bf16x8 af;
      const unsigned int* a0p = (const unsigned int*)&u0[kk];
      const unsigned int* a1p = (const unsigned int*)&u1[kk];
      #pragma unroll
      for (int i2 = 0; i2 < 4; ++i2) {
        float a0 = w0 * bf_lo(a0p[i2]) + w1 * bf_lo(a1p[i2]);
        float a1 = w0 * bf_hi(a0p[i2]) + w1 * bf_hi(a1p[i2]);
        ((unsigned int*)&af)[i2] = cvt_pk_bf16(a0, a1);
      }
      #pragma unroll
      for (int ctt = 0; ctt < 4; ++ctt)
        acc[ctt] = __builtin_amdgcn_mfma_f32_16x16x32_bf16(af, bv[kk][ctt], acc[ctt], 0, 0, 0);
    }
  }

  __shared__ float Pp[2][16][64];
  if (kh == 1) {
    #pragma unroll
    for (int ctt = 0; ctt < 4; ++ctt)
      #pragma unroll
      for (int r = 0; r < 4; ++r)
        Pp[oo][q4 * 4 + r][ctt * 16 + n16] = acc[ctt][r];
  }
  __syncthreads();
  if (kh == 1) return;
  #pragma unroll
  for (int ctt = 0; ctt < 4; ++ctt)
    #pragma unroll
    for (int r = 0; r < 4; ++r)
      acc[ctt][r] += Pp[oo][q4 * 4 + r][ctt * 16 + n16];

  const float kqb0 = kq_b[h0], kqb1 = kq_b[h0 + 1];
  float tw[4];
  #pragma unroll
  for (int r = 0; r < 4; ++r) {
    int qr = qt16 * 16 + q4 * 4 + r;
    float2 s0 = *(const float2*)(rs + ((((size_t)(b * 16 + h0)     << 10) + qr) << 1));
    float2 s1 = *(const float2*)(rs + ((((size_t)(b * 16 + h0 + 1) << 10) + qr) << 1));
    tw[r] = (Tc > 0) ? (mwa * s0.y * __expf(kqb0 - s0.x) +
                        mwb * s1.y * __expf(kqb1 - s1.x)) : 0.f;
  }
  const float mb = mix_b[ho];
  const float alpha = dyt_alpha[0], dsc = depth_scale[0];
  const float* vt = Vtail + (size_t)(b * 16 + ho) * 17 * 64;
  #pragma unroll
  for (int ctt = 0; ctt < 4; ++ctt) {
    int d = ctt * 16 + n16;
    float vtn = vt[(size_t)nkt * 64 + d];
    float vt0 = vt[d];
    float wgt = dyt_w[d], bds = dyt_b[d];
    #pragma unroll
    for (int r = 0; r < 4; ++r) {
      float v = acc[ctt][r] + tw[r] * vtn + mb * vt0;
      float e = __expf(2.f * alpha * v);
      float th = 1.f - 2.f / (e + 1.f);
      float y = (th * wgt + bds) * dsc;
      int qr = qt16 * 16 + q4 * 4 + r;
      out_attn[(((size_t)(b * 1024 + qr)) << 10) + ho * 64 + d] = (bf16)y;
    }
  }
}

// ---------------------------------------------------------------------------
extern "C" void kernel_launch(void* const* d_in, const int* in_sizes, int n_in,
                              void* d_out, int out_size, void* d_ws, size_t ws_size,
                              hipStream_t stream) {
  const float* Q    = (const float*)d_in[0];
  const float* Kx   = (const float*)d_in[1];
  const float* V    = (const float*)d_in[2];
  const float* Wq   = (const float*)d_in[3];
  const float* bq   = (const float*)d_in[4];
  const float* Wk   = (const float*)d_in[5];
  const float* bk   = (const float*)d_in[6];
  const float* Wv   = (const float*)d_in[7];
  const float* bv   = (const float*)d_in[8];
  const float* Wo   = (const float*)d_in[9];
  const float* bo   = (const float*)d_in[10];
  const float* kq_w = (const float*)d_in[11];
  const float* kq_b = (const float*)d_in[12];
  const float* mixw = (const float*)d_in[13];
  const float* mixb = (const float*)d_in[14];
  const float* dyta = (const float*)d_in[15];
  const float* dytw = (const float*)d_in[16];
  const float* dytb = (const float*)d_in[17];
  const float* dsc  = (const float*)d_in[18];

  char* ws = (char*)d_ws;
  bf16* qh     = (bf16*)(ws);                              // 4 MB (kh, V2 follow)
  float* tstat = (float*)(ws + (size_t)(12 << 20));        // 2.42 MB (alive thru pv)
  float* Vtail = (float*)(ws + (size_t)(16 << 20));        // 136 KB
  float* Tsum  = (float*)(ws + (size_t)(16 << 20) + (256 << 10)); // 128 KB
  float* rsbuf = (float*)(ws + (size_t)(16 << 20) + (512 << 10)); // 256 KB
  bf16* WtT    = (bf16*)(ws + (size_t)(17 << 20));         // 8 MB (4 planes x 2MB)
  bf16* oat    = (bf16*)(ws + (size_t)(17 << 20));         // 4 MB, aliases Wq/Wk planes
  bf16* conv   = (bf16*)(ws + (size_t)(25 << 20));         // 39.58 MB (P2 tiles)
  bf16* kh     = qh + ((size_t)1 << 21);
  bf16* V2     = qh + ((size_t)2 << 21);

  wtr_k<<<dim3(16, 16, 4), 256, 0, stream>>>(Wq, Wk, Wv, Wo, WtT);
  proj_gemm_k<<<dim3(16, 32, 3), 256, 0, stream>>>(Q, Kx, V, WtT, bq, bk, bv, qh);
  vtile_sum_k<<<dim3(16, 16, 2), 64, 0, stream>>>(V2, Tsum);
  vtail_k<<<dim3(16, 2), 64, 0, stream>>>(Tsum, Vtail);
  logits_conv_k<<<dim3(151, 16, 2), 320, 0, stream>>>(qh, kh, kq_w, kq_b, conv, tstat);
  combine_k<<<dim3(128), 256, 0, stream>>>(tstat, kq_b, rsbuf);
  pv_k<<<dim3(64, 8, 2), 256, 0, stream>>>(conv, V2, rsbuf, tstat, Vtail, mixw, mixb, kq_b,
                                           dyta, dytw, dytb, dsc, oat);
  out_gemm_k<<<dim3(16, 32), 256, 0, stream>>>(oat, WtT + ((size_t)3 << 20), bo, (float*)d_out);
}

// Round 10
// 221.880 us; speedup vs baseline: 1.2962x; 1.0248x over previous
//
#include <hip/hip_runtime.h>
#include <cstdint>
#include <cstddef>

typedef __bf16 bf16;
typedef __bf16 bf16x8 __attribute__((ext_vector_type(8)));
typedef float f32x4 __attribute__((ext_vector_type(4)));

#define DEVI static __device__ __forceinline__

// pack two f32 -> two bf16 (RTNE) in one uint
DEVI unsigned int cvt_pk_bf16(float lo, float hi) {
  unsigned int bl = __float_as_uint(lo);
  bl += 0x7fffu + ((bl >> 16) & 1u);
  unsigned int bh = __float_as_uint(hi);
  bh += 0x7fffu + ((bh >> 16) & 1u);
  return (bl >> 16) | (bh & 0xffff0000u);
}
DEVI float bf_lo(unsigned int u) { return __uint_as_float(u << 16); }
DEVI float bf_hi(unsigned int u) { return __uint_as_float(u & 0xffff0000u); }

// ---------------------------------------------------------------------------
// W transpose prepass: W (1024x1024 f32, [k][n]) -> Wt (bf16 [n][k]).
// ---------------------------------------------------------------------------
__global__ __launch_bounds__(256) void wtr_k(
    const float* __restrict__ Wq, const float* __restrict__ Wk,
    const float* __restrict__ Wv, const float* __restrict__ Wo,
    bf16* __restrict__ Wt)
{
  const int z = blockIdx.z;
  const float* W = (z == 0) ? Wq : (z == 1) ? Wk : (z == 2) ? Wv : Wo;
  bf16* out = Wt + ((size_t)z << 20);
  const int n0 = blockIdx.x * 64, k0 = blockIdx.y * 64;
  __shared__ bf16 Ts[64 * 72];
  const int tid = threadIdx.x;
  #pragma unroll
  for (int i = 0; i < 4; ++i) {
    int t = tid + i * 256;
    int kr = t >> 4, nc = t & 15;
    float4 v = *(const float4*)(W + (size_t)(k0 + kr) * 1024 + n0 + nc * 4);
    Ts[(nc * 4 + 0) * 72 + kr] = (bf16)v.x;
    Ts[(nc * 4 + 1) * 72 + kr] = (bf16)v.y;
    Ts[(nc * 4 + 2) * 72 + kr] = (bf16)v.z;
    Ts[(nc * 4 + 3) * 72 + kr] = (bf16)v.w;
  }
  __syncthreads();
  const int n = tid >> 2, kc = tid & 3;
  *(uint4*)(out + (size_t)(n0 + n) * 1024 + k0 + kc * 16) =
      *(const uint4*)(&Ts[n * 72 + kc * 16]);
  *(uint4*)(out + (size_t)(n0 + n) * 1024 + k0 + kc * 16 + 8) =
      *(const uint4*)(&Ts[n * 72 + kc * 16 + 8]);
}

// ---------------------------------------------------------------------------
// Fused projection GEMM, f32 A staged inline to bf16, register prefetch.
// grid (512,1,3), XCD-aware decode: m0 = (bid&31) fastest -> the 16 blocks
// sharing an A-stripe land on ONE XCD (bid%8 == m0idx%8), A fetched once/L2.
// z=0 Q->qh, z=1 K->kh (B,H,S,HD); z=2: V -> V2 in PV B-fragment order.
// ---------------------------------------------------------------------------
__global__ __launch_bounds__(256) void proj_gemm_k(
    const float* __restrict__ Q, const float* __restrict__ K,
    const float* __restrict__ V, const bf16* __restrict__ Wt,
    const float* __restrict__ bq, const float* __restrict__ bk,
    const float* __restrict__ bv, bf16* __restrict__ outbase)
{
  const int z = blockIdx.z;
  const float* A = (z == 0) ? Q : (z == 1) ? K : V;
  const bf16* Bt = Wt + ((size_t)z << 20);
  const float* bias = (z == 0) ? bq : (z == 1) ? bk : bv;
  bf16* outb = outbase + ((size_t)z << 21);

  __shared__ __align__(16) char sm[10240];
  bf16* As = (bf16*)sm;
  bf16* Bs = As + 64 * 40;
  bf16* T2 = (bf16*)sm;            // [64 d][72 s] (aliases, post-loop z==2)

  const int tid = threadIdx.x, lane = tid & 63, wid = tid >> 6;
  const int q4 = lane >> 4, n16 = lane & 15;
  const int wm = wid >> 1, wn = wid & 1;
  const int bid = blockIdx.x;
  const int m0 = (bid & 31) * 64, n0 = (bid >> 5) * 64;   // m fastest: XCD swizzle
  const int brow = tid >> 2, bc = tid & 3;
  f32x4 acc[2][2] = {};

  float4 aR0 = *(const float4*)(A + (size_t)(m0 + brow) * 1024 + bc * 8);
  float4 aR1 = *(const float4*)(A + (size_t)(m0 + brow) * 1024 + bc * 8 + 4);
  uint4 bR = *(const uint4*)(Bt + (size_t)(n0 + brow) * 1024 + bc * 8);
  for (int kb = 0; kb < 32; ++kb) {
    __syncthreads();
    *(uint2*)(&As[brow * 40 + bc * 8]) =
        make_uint2(cvt_pk_bf16(aR0.x, aR0.y), cvt_pk_bf16(aR0.z, aR0.w));
    *(uint2*)(&As[brow * 40 + bc * 8 + 4]) =
        make_uint2(cvt_pk_bf16(aR1.x, aR1.y), cvt_pk_bf16(aR1.z, aR1.w));
    *(uint4*)(&Bs[brow * 40 + bc * 8]) = bR;
    __syncthreads();
    if (kb < 31) {
      const int k1 = (kb + 1) * 32;
      aR0 = *(const float4*)(A + (size_t)(m0 + brow) * 1024 + k1 + bc * 8);
      aR1 = *(const float4*)(A + (size_t)(m0 + brow) * 1024 + k1 + bc * 8 + 4);
      bR  = *(const uint4*)(Bt + (size_t)(n0 + brow) * 1024 + k1 + bc * 8);
    }
    bf16x8 af[2], bfv[2];
    #pragma unroll
    for (int rt = 0; rt < 2; ++rt)
      af[rt] = *(const bf16x8*)(&As[(wm * 32 + rt * 16 + n16) * 40 + q4 * 8]);
    #pragma unroll
    for (int ct = 0; ct < 2; ++ct)
      bfv[ct] = *(const bf16x8*)(&Bs[(wn * 32 + ct * 16 + n16) * 40 + q4 * 8]);
    #pragma unroll
    for (int rt = 0; rt < 2; ++rt)
      #pragma unroll
      for (int ct = 0; ct < 2; ++ct)
        acc[rt][ct] = __builtin_amdgcn_mfma_f32_16x16x32_bf16(af[rt], bfv[ct], acc[rt][ct], 0, 0, 0);
  }

  if (z < 2) {   // (B,H,S,HD)
    #pragma unroll
    for (int ct = 0; ct < 2; ++ct) {
      int col = n0 + wn * 32 + ct * 16 + n16;
      float bvl = bias[col];
      int h = col >> 6, d = col & 63;
      #pragma unroll
      for (int rt = 0; rt < 2; ++rt) {
        #pragma unroll
        for (int r = 0; r < 4; ++r) {
          int row = m0 + wm * 32 + rt * 16 + q4 * 4 + r;
          int b2 = row >> 10, s = row & 1023;
          outb[((size_t)((b2 * 16 + h) * 1024 + s) << 6) + d] =
              (bf16)(acc[rt][ct][r] + bvl);
        }
      }
    }
  } else {       // V2 fragment layout
    __syncthreads();
    #pragma unroll
    for (int ct = 0; ct < 2; ++ct) {
      int cl = wn * 32 + ct * 16 + n16;
      float bvl = bias[n0 + cl];
      #pragma unroll
      for (int rt = 0; rt < 2; ++rt)
        #pragma unroll
        for (int r = 0; r < 4; ++r) {
          int rl = wm * 32 + rt * 16 + q4 * 4 + r;
          T2[cl * 72 + rl] = (bf16)(acc[rt][ct][r] + bvl);
        }
    }
    __syncthreads();
    const int b2 = m0 >> 10, kt = (m0 & 1023) >> 6, h = n0 >> 6;
    bf16* vout = outb + ((size_t)(b2 * 16 + h) << 16) + kt * 4096;
    #pragma unroll
    for (int i = 0; i < 2; ++i) {
      int c = tid + i * 256;                 // 0..511 16B-chunks
      int kk = c >> 8, ctt = (c >> 6) & 3, q4c = (c >> 4) & 3, n16c = c & 15;
      uint4 v = *(const uint4*)(&T2[(ctt * 16 + n16c) * 72 + kk * 32 + q4c * 8]);
      *(uint4*)(vout + kk * 2048 + ctt * 512 + (q4c * 16 + n16c) * 8) = v;
    }
  }
}

// ---------------------------------------------------------------------------
// Output GEMM: d_out = oat(2048x1024 bf16) @ WoT + bo, f32 out. Prefetched.
// grid 512, XCD-aware decode (m fastest) like proj_gemm.
// ---------------------------------------------------------------------------
__global__ __launch_bounds__(256) void out_gemm_k(
    const bf16* __restrict__ Ab, const bf16* __restrict__ Bt,
    const float* __restrict__ bias, float* __restrict__ outf)
{
  __shared__ __align__(16) char sm[10240];
  bf16* As = (bf16*)sm;
  bf16* Bs = As + 64 * 40;
  const int tid = threadIdx.x, lane = tid & 63, wid = tid >> 6;
  const int q4 = lane >> 4, n16 = lane & 15;
  const int wm = wid >> 1, wn = wid & 1;
  const int bid = blockIdx.x;
  const int m0 = (bid & 31) * 64, n0 = (bid >> 5) * 64;   // XCD swizzle
  const int brow = tid >> 2, bc = tid & 3;
  f32x4 acc[2][2] = {};

  uint4 aR = *(const uint4*)(Ab + (size_t)(m0 + brow) * 1024 + bc * 8);
  uint4 bR = *(const uint4*)(Bt + (size_t)(n0 + brow) * 1024 + bc * 8);
  for (int kb = 0; kb < 32; ++kb) {
    __syncthreads();
    *(uint4*)(&As[brow * 40 + bc * 8]) = aR;
    *(uint4*)(&Bs[brow * 40 + bc * 8]) = bR;
    __syncthreads();
    if (kb < 31) {
      const int k1 = (kb + 1) * 32;
      aR = *(const uint4*)(Ab + (size_t)(m0 + brow) * 1024 + k1 + bc * 8);
      bR = *(const uint4*)(Bt + (size_t)(n0 + brow) * 1024 + k1 + bc * 8);
    }
    bf16x8 af[2], bfv[2];
    #pragma unroll
    for (int rt = 0; rt < 2; ++rt)
      af[rt] = *(const bf16x8*)(&As[(wm * 32 + rt * 16 + n16) * 40 + q4 * 8]);
    #pragma unroll
    for (int ct = 0; ct < 2; ++ct)
      bfv[ct] = *(const bf16x8*)(&Bs[(wn * 32 + ct * 16 + n16) * 40 + q4 * 8]);
    #pragma unroll
    for (int rt = 0; rt < 2; ++rt)
      #pragma unroll
      for (int ct = 0; ct < 2; ++ct)
        acc[rt][ct] = __builtin_amdgcn_mfma_f32_16x16x32_bf16(af[rt], bfv[ct], acc[rt][ct], 0, 0, 0);
  }
  #pragma unroll
  for (int ct = 0; ct < 2; ++ct) {
    int col = n0 + wn * 32 + ct * 16 + n16;
    float bvl = bias[col];
    #pragma unroll
    for (int rt = 0; rt < 2; ++rt)
      #pragma unroll
      for (int r = 0; r < 4; ++r) {
        int row = m0 + wm * 32 + rt * 16 + q4 * 4 + r;
        outf[(size_t)row * 1024 + col] = acc[rt][ct][r] + bvl;
      }
  }
}

// ---------------------------------------------------------------------------
// per-(b,h,ktile) column sums of v (V2 fragment layout) + suffix scan
// ---------------------------------------------------------------------------
__global__ void vtile_sum_k(const bf16* __restrict__ V2, float* __restrict__ Tsum)
{
  int kt = blockIdx.x, h = blockIdx.y, b = blockIdx.z, d = threadIdx.x;
  int ctt = d >> 4, n16c = d & 15;
  const bf16* p = V2 + ((size_t)(b * 16 + h) << 16) + kt * 4096 + ctt * 512 + n16c * 8;
  float s = 0.f;
  #pragma unroll
  for (int kk = 0; kk < 2; ++kk)
    #pragma unroll
    for (int q4i = 0; q4i < 4; ++q4i)
      #pragma unroll
      for (int j = 0; j < 8; ++j)
        s += (float)p[kk * 2048 + q4i * 128 + j];
  Tsum[((b * 16 + h) * 16 + kt) * 64 + d] = s;
}

__global__ void vtail_k(const float* __restrict__ Tsum, float* __restrict__ Vtail)
{
  int h = blockIdx.x, b = blockIdx.y, d = threadIdx.x;
  float c = 0.f;
  Vtail[((b * 16 + h) * 17 + 16) * 64 + d] = 0.f;
  for (int kt = 15; kt >= 0; --kt) {
    c += Tsum[((b * 16 + h) * 16 + kt) * 64 + d];
    Vtail[((b * 16 + h) * 17 + kt) * 64 + d] = c;
  }
}

// ---------------------------------------------------------------------------
// K2: logits + 3x3 conv -> P = exp(conv - tile_row_max) stored in PV A-frag
// order, plus (mxt, sumP) per tile row. Kst/Ls LDS union (18.4 KB).
// ---------------------------------------------------------------------------
__global__ __launch_bounds__(320) void logits_conv_k(
    const bf16* __restrict__ qh, const bf16* __restrict__ kh,
    const float* __restrict__ kq_w, const float* __restrict__ kq_b,
    bf16* __restrict__ conv_out, float* __restrict__ tstats)
{
  const int tt = blockIdx.x;
  int qt = 0, base = 0;
  while (qt < 15 && base + qt + 2 <= tt) { base += qt + 2; ++qt; }
  const int ct = tt - base;
  const int h = blockIdx.y, b = blockIdx.z;
  const int q0 = qt * 64, c0 = ct * 64;
  __shared__ __align__(16) char un[18432];      // union: Kst then Ls
  bf16* Kst = (bf16*)un;                        // [80][72] bf16, staging
  float* Ls = (float*)un;                       // [66][68] f32, logits halo
  const int tid = threadIdx.x;
  const int lane = tid & 63, wid = tid >> 6;    // 5 waves
  const int q4 = lane >> 4, n16 = lane & 15;
  const bf16* qb = qh + ((size_t)(b * 16 + h) << 16);
  const bf16* kb = kh + ((size_t)(b * 16 + h) << 16);

  // ---- A-fragments straight from global (issue first, overlap staging) ----
  const int ar = min(max(q0 - 2 + wid * 16 + n16, 0), 1023);
  bf16x8 a0 = *(const bf16x8*)(qb + ar * 64 + q4 * 8);
  bf16x8 a1 = *(const bf16x8*)(qb + ar * 64 + 32 + q4 * 8);

  // ---- coalesced K staging (contiguous 10 KB span) ----
  for (int t = tid; t < 640; t += 320) {
    int row = t >> 3, ch = t & 7;
    int br = min(max(c0 - 1 + row, 0), 1023);
    *(uint4*)(&Kst[row * 72 + ch * 8]) = *(const uint4*)(kb + br * 64 + ch * 8);
  }
  __syncthreads();

  // ---- QK^T (B-frags from LDS) ----
  f32x4 acc[5] = {};
  #pragma unroll
  for (int c5 = 0; c5 < 5; ++c5) {
    int brow = c5 * 16 + n16;
    bf16x8 b0 = *(const bf16x8*)(&Kst[brow * 72 + q4 * 8]);
    bf16x8 b1 = *(const bf16x8*)(&Kst[brow * 72 + 32 + q4 * 8]);
    acc[c5] = __builtin_amdgcn_mfma_f32_16x16x32_bf16(a0, b0, acc[c5], 0, 0, 0);
    acc[c5] = __builtin_amdgcn_mfma_f32_16x16x32_bf16(a1, b1, acc[c5], 0, 0, 0);
  }
  __syncthreads();   // Kst reads complete before Ls overwrites the union

  #pragma unroll
  for (int c5 = 0; c5 < 5; ++c5) {
    #pragma unroll
    for (int r = 0; r < 4; ++r) {
      int Lrow = wid * 16 + q4 * 4 + r;
      int Lcol = c5 * 16 + n16;
      if (Lrow < 66 && Lcol < 66) {
        int rg = q0 - 2 + Lrow;
        int cg = c0 - 1 + Lcol;
        float v = (cg >= 0 && cg <= rg) ? acc[c5][r] * 0.125f : 0.f;
        Ls[Lrow * 68 + Lcol] = v;
      }
    }
  }
  __syncthreads();

  if (tid < 256) {
    float w9[9];
    #pragma unroll
    for (int i = 0; i < 9; ++i) w9[i] = kq_w[h * 9 + i];
    const float bb = kq_b[h];
    const size_t tplane = (size_t)(b * 16 + h) * 151 + base + ct;
    bf16* tb = conv_out + tplane * 4096;
    float2* st = (float2*)tstats + tplane * 64;

    const int r = tid >> 2, qr = tid & 3;   // output row, 16-col quarter
    float4 R0[5], R1[5], R2[5];
    const float* L0 = &Ls[r * 68 + qr * 16];
    #pragma unroll
    for (int i = 0; i < 5; ++i) {
      R0[i] = *(const float4*)(L0 + i * 4);
      R1[i] = *(const float4*)(L0 + 68 + i * 4);
      R2[i] = *(const float4*)(L0 + 136 + i * 4);
    }
    const float* f0 = (const float*)R0;
    const float* f1 = (const float*)R1;
    const float* f2 = (const float*)R2;
    float o[16];
    #pragma unroll
    for (int jj = 0; jj < 16; ++jj)
      o[jj] = bb + w9[0]*f0[jj] + w9[1]*f0[jj+1] + w9[2]*f0[jj+2]
                 + w9[3]*f1[jj] + w9[4]*f1[jj+1] + w9[5]*f1[jj+2]
                 + w9[6]*f2[jj] + w9[7]*f2[jj+1] + w9[8]*f2[jj+2];
    float mx = o[0];
    #pragma unroll
    for (int jj = 1; jj < 16; ++jj) mx = fmaxf(mx, o[jj]);
    mx = fmaxf(mx, __shfl_xor(mx, 1));
    mx = fmaxf(mx, __shfl_xor(mx, 2));
    unsigned int p[8];
    #pragma unroll
    for (int jj = 0; jj < 8; ++jj)
      p[jj] = cvt_pk_bf16(__expf(o[2*jj] - mx), __expf(o[2*jj+1] - mx));
    // store in PV A-frag order: [sr][kk][q4*16+n16][8]
    const int kk = qr >> 1, q4b = (qr & 1) * 2, sr = r >> 4, n16r = r & 15;
    *(uint4*)(tb + (sr * 2 + kk) * 512 + (q4b * 16 + n16r) * 8)       = *(const uint4*)&p[0];
    *(uint4*)(tb + (sr * 2 + kk) * 512 + ((q4b + 1) * 16 + n16r) * 8) = *(const uint4*)&p[4];
    float s = 0.f;
    #pragma unroll
    for (int jj = 0; jj < 8; ++jj) s += bf_lo(p[jj]) + bf_hi(p[jj]);
    s += __shfl_xor(s, 1);
    s += __shfl_xor(s, 2);
    if (qr == 0) st[r] = make_float2(mx, s);
  }
}

// ---------------------------------------------------------------------------
// K3a: combine per-tile stats -> per-row (max m, 1/l) incl. constant tail
// ---------------------------------------------------------------------------
__global__ __launch_bounds__(256) void combine_k(
    const float* __restrict__ tstats, const float* __restrict__ kq_b,
    float* __restrict__ rs)
{
  const int ridx = blockIdx.x * 256 + threadIdx.x;
  const int q = ridx & 1023, h = (ridx >> 10) & 15, plane = ridx >> 10;
  const int qt = q >> 6;
  const int nkt = min(qt + 2, 16);
  const int Tc = 1024 - (nkt << 6);
  const float2* ts = (const float2*)tstats +
      ((size_t)plane * 151 + (size_t)(qt * (qt + 3) / 2)) * 64 + (q & 63);
  const float kb = kq_b[h];
  float mx = (Tc > 0) ? kb : -3.0e38f;
  for (int kt = 0; kt < nkt; ++kt) mx = fmaxf(mx, ts[(size_t)kt * 64].x);
  float s = (float)Tc * __expf(kb - mx);
  for (int kt = 0; kt < nkt; ++kt) {
    float2 v = ts[(size_t)kt * 64];
    s += v.y * __expf(v.x - mx);
  }
  rs[(size_t)ridx * 2]     = mx;
  rs[(size_t)ridx * 2 + 1] = 1.f / s;
}

// ---------------------------------------------------------------------------
// K3b: PV from fragment-ordered P and V2 — every load 64-lane contiguous.
// A_o = sum_j (mw[o,j]*rinv_j*exp(mxt_j-m_j))*P_j
// ---------------------------------------------------------------------------
__global__ __launch_bounds__(256) void pv_k(
    const bf16* __restrict__ conv_out, const bf16* __restrict__ V2,
    const float* __restrict__ rs, const float* __restrict__ tstats,
    const float* __restrict__ Vtail,
    const float* __restrict__ mix_w, const float* __restrict__ mix_b,
    const float* __restrict__ kq_b,
    const float* __restrict__ dyt_alpha, const float* __restrict__ dyt_w,
    const float* __restrict__ dyt_b, const float* __restrict__ depth_scale,
    bf16* __restrict__ out_attn)
{
  const int qt16 = blockIdx.x, g = blockIdx.y, b = blockIdx.z;
  const int qt = qt16 >> 2;
  const int nkt = min(qt + 2, 16);
  const int Tc = 1024 - (nkt << 6);
  const int tid = threadIdx.x, lane = tid & 63, wid = tid >> 6;
  const int q4 = lane >> 4, n16 = lane & 15;
  const int oo = wid >> 1, kh = wid & 1;
  const int h0 = 2 * g, ho = h0 + oo;
  const int sr = qt16 & 3, strow = sr * 16;
  const size_t tbase = (size_t)(qt * (qt + 3) / 2);

  const int qrow = qt16 * 16 + n16;
  const float2 r0 = *(const float2*)(rs + ((((size_t)(b * 16 + h0)     << 10) + qrow) << 1));
  const float2 r1 = *(const float2*)(rs + ((((size_t)(b * 16 + h0 + 1) << 10) + qrow) << 1));
  const float m0 = r0.x, m1 = r1.x;
  const float mwa = mix_w[ho * 2 + 0], mwb = mix_w[ho * 2 + 1];
  const float wa = mwa * r0.y, wb = mwb * r1.y;   // mw * rinv

  const bf16* pb0 = conv_out +
      ((size_t)(b * 16 + h0) * 151 + tbase) * 4096 + sr * 1024 + lane * 8;
  const bf16* pb1 = pb0 + (size_t)151 * 4096;
  const float2* ts0 = (const float2*)tstats +
      ((size_t)(b * 16 + h0) * 151 + tbase) * 64 + strow + n16;
  const float2* ts1 = ts0 + (size_t)151 * 64;
  const bf16* vb = V2 + ((size_t)(b * 16 + ho) << 16) + lane * 8;

  const int niter = (nkt - kh + 1) >> 1;
  float wk0[8], wk1[8];
  #pragma unroll
  for (int i = 0; i < 8; ++i) {
    int ktc = (i < niter) ? (kh + 2 * i) : 0;
    wk0[i] = wa * __expf(ts0[(size_t)ktc * 64].x - m0);
    wk1[i] = wb * __expf(ts1[(size_t)ktc * 64].x - m1);
  }

  f32x4 acc[4] = {};
  int ii = 0;
  for (int kt = kh; kt < nkt; kt += 2, ++ii) {
    uint4 u0[2], u1[2];
    #pragma unroll
    for (int kk = 0; kk < 2; ++kk) {
      u0[kk] = *(const uint4*)(pb0 + (size_t)kt * 4096 + kk * 512);
      u1[kk] = *(const uint4*)(pb1 + (size_t)kt * 4096 + kk * 512);
    }
    bf16x8 bv[2][4];
    #pragma unroll
    for (int kk = 0; kk < 2; ++kk)
      #pragma unroll
      for (int ctt = 0; ctt < 4; ++ctt)
        bv[kk][ctt] = *(const bf16x8*)(vb + (size_t)kt * 4096 + kk * 2048 + ctt * 512);
    const float w0 = wk0[ii], w1 = wk1[ii];
    #pragma unroll
    for (int kk = 0; kk < 2; ++kk) {
      bf16x8 af;
      const unsigned int* a0p = (const unsigned int*)&u0[kk];
      const unsigned int* a1p = (const unsigned int*)&u1[kk];
      #pragma unroll
      for (int i2 = 0; i2 < 4; ++i2) {
        float a0 = w0 * bf_lo(a0p[i2]) + w1 * bf_lo(a1p[i2]);
        float a1 = w0 * bf_hi(a0p[i2]) + w1 * bf_hi(a1p[i2]);
        ((unsigned int*)&af)[i2] = cvt_pk_bf16(a0, a1);
      }
      #pragma unroll
      for (int ctt = 0; ctt < 4; ++ctt)
        acc[ctt] = __builtin_amdgcn_mfma_f32_16x16x32_bf16(af, bv[kk][ctt], acc[ctt], 0, 0, 0);
    }
  }

  __shared__ float Pp[2][16][64];
  if (kh == 1) {
    #pragma unroll
    for (int ctt = 0; ctt < 4; ++ctt)
      #pragma unroll
      for (int r = 0; r < 4; ++r)
        Pp[oo][q4 * 4 + r][ctt * 16 + n16] = acc[ctt][r];
  }
  __syncthreads();
  if (kh == 1) return;
  #pragma unroll
  for (int ctt = 0; ctt < 4; ++ctt)
    #pragma unroll
    for (int r = 0; r < 4; ++r)
      acc[ctt][r] += Pp[oo][q4 * 4 + r][ctt * 16 + n16];

  const float kqb0 = kq_b[h0], kqb1 = kq_b[h0 + 1];
  float tw[4];
  #pragma unroll
  for (int r = 0; r < 4; ++r) {
    int qr = qt16 * 16 + q4 * 4 + r;
    float2 s0 = *(const float2*)(rs + ((((size_t)(b * 16 + h0)     << 10) + qr) << 1));
    float2 s1 = *(const float2*)(rs + ((((size_t)(b * 16 + h0 + 1) << 10) + qr) << 1));
    tw[r] = (Tc > 0) ? (mwa * s0.y * __expf(kqb0 - s0.x) +
                        mwb * s1.y * __expf(kqb1 - s1.x)) : 0.f;
  }
  const float mb = mix_b[ho];
  const float alpha = dyt_alpha[0], dsc = depth_scale[0];
  const float* vt = Vtail + (size_t)(b * 16 + ho) * 17 * 64;
  #pragma unroll
  for (int ctt = 0; ctt < 4; ++ctt) {
    int d = ctt * 16 + n16;
    float vtn = vt[(size_t)nkt * 64 + d];
    float vt0 = vt[d];
    float wgt = dyt_w[d], bds = dyt_b[d];
    #pragma unroll
    for (int r = 0; r < 4; ++r) {
      float v = acc[ctt][r] + tw[r] * vtn + mb * vt0;
      float e = __expf(2.f * alpha * v);
      float th = 1.f - 2.f / (e + 1.f);
      float y = (th * wgt + bds) * dsc;
      int qr = qt16 * 16 + q4 * 4 + r;
      out_attn[(((size_t)(b * 1024 + qr)) << 10) + ho * 64 + d] = (bf16)y;
    }
  }
}

// ---------------------------------------------------------------------------
extern "C" void kernel_launch(void* const* d_in, const int* in_sizes, int n_in,
                              void* d_out, int out_size, void* d_ws, size_t ws_size,
                              hipStream_t stream) {
  const float* Q    = (const float*)d_in[0];
  const float* Kx   = (const float*)d_in[1];
  const float* V    = (const float*)d_in[2];
  const float* Wq   = (const float*)d_in[3];
  const float* bq   = (const float*)d_in[4];
  const float* Wk   = (const float*)d_in[5];
  const float* bk   = (const float*)d_in[6];
  const float* Wv   = (const float*)d_in[7];
  const float* bv   = (const float*)d_in[8];
  const float* Wo   = (const float*)d_in[9];
  const float* bo   = (const float*)d_in[10];
  const float* kq_w = (const float*)d_in[11];
  const float* kq_b = (const float*)d_in[12];
  const float* mixw = (const float*)d_in[13];
  const float* mixb = (const float*)d_in[14];
  const float* dyta = (const float*)d_in[15];
  const float* dytw = (const float*)d_in[16];
  const float* dytb = (const float*)d_in[17];
  const float* dsc  = (const float*)d_in[18];

  char* ws = (char*)d_ws;
  bf16* qh     = (bf16*)(ws);                              // 4 MB (kh, V2 follow)
  float* tstat = (float*)(ws + (size_t)(12 << 20));        // 2.42 MB (alive thru pv)
  float* Vtail = (float*)(ws + (size_t)(16 << 20));        // 136 KB
  float* Tsum  = (float*)(ws + (size_t)(16 << 20) + (256 << 10)); // 128 KB
  float* rsbuf = (float*)(ws + (size_t)(16 << 20) + (512 << 10)); // 256 KB
  bf16* WtT    = (bf16*)(ws + (size_t)(17 << 20));         // 8 MB (4 planes x 2MB)
  bf16* oat    = (bf16*)(ws + (size_t)(17 << 20));         // 4 MB, aliases Wq/Wk planes
  bf16* conv   = (bf16*)(ws + (size_t)(25 << 20));         // 39.58 MB (P2 tiles)
  bf16* kh     = qh + ((size_t)1 << 21);
  bf16* V2     = qh + ((size_t)2 << 21);

  wtr_k<<<dim3(16, 16, 4), 256, 0, stream>>>(Wq, Wk, Wv, Wo, WtT);
  proj_gemm_k<<<dim3(512, 1, 3), 256, 0, stream>>>(Q, Kx, V, WtT, bq, bk, bv, qh);
  vtile_sum_k<<<dim3(16, 16, 2), 64, 0, stream>>>(V2, Tsum);
  vtail_k<<<dim3(16, 2), 64, 0, stream>>>(Tsum, Vtail);
  logits_conv_k<<<dim3(151, 16, 2), 320, 0, stream>>>(qh, kh, kq_w, kq_b, conv, tstat);
  combine_k<<<dim3(128), 256, 0, stream>>>(tstat, kq_b, rsbuf);
  pv_k<<<dim3(64, 8, 2), 256, 0, stream>>>(conv, V2, rsbuf, tstat, Vtail, mixw, mixb, kq_b,
                                           dyta, dytw, dytb, dsc, oat);
  out_gemm_k<<<dim3(512), 256, 0, stream>>>(oat, WtT + ((size_t)3 << 20), bo, (float*)d_out);
}